// Round 1
// baseline (1133.208 us; speedup 1.0000x reference)
//
#include <hip/hip_runtime.h>

#define NNODES 20000
#define NEDGES 320000
#define FIN    512
#define HC1    512      // H1*HID
#define NHEAD  8
#define OUT2   49
#define NCOL2  392      // NHEAD*OUT2
#define NB2    784      // 2*NCOL2
#define NCLU   64
#define NIDX   10000
#define NEG    0.2f

static __device__ __forceinline__ float lrelu(float v){ return v > 0.f ? v : NEG*v; }

// ---------------- GEMM: C[M,Ncols] = A[M,512] @ B[512,Ncols], fp32 ----------------
#define BM 128
#define BN 128
#define BK 16

template<int EPI>
__global__ __launch_bounds__(256) void gemm_kernel(
    const float* __restrict__ A, const float* __restrict__ B,
    float* __restrict__ C, int M, int Ncols,
    const int* __restrict__ cmax, const float* __restrict__ CFW, float* __restrict__ h2)
{
  __shared__ float As[BK][BM+4];
  __shared__ float Bs[BK][BN+4];
  const int K = 512;
  int tid = threadIdx.x;
  int row0 = blockIdx.x * BM;
  int col0 = blockIdx.y * BN;
  int tr = (tid >> 4) << 3;
  int tc = (tid & 15) << 3;
  int ar = tid >> 2;            // 0..63
  int ac = (tid & 3) << 2;      // 0,4,8,12
  int br = tid >> 5;            // 0..7
  int bc = (tid & 31) << 2;     // 0..124
  float acc[8][8] = {};

  for (int k0 = 0; k0 < K; k0 += BK) {
    {
      int m0 = row0 + ar;
      float4 v = (m0 < M) ? *(const float4*)(A + (size_t)m0*K + (k0+ac)) : make_float4(0.f,0.f,0.f,0.f);
      As[ac+0][ar] = v.x; As[ac+1][ar] = v.y; As[ac+2][ar] = v.z; As[ac+3][ar] = v.w;
      int m1 = m0 + 64;
      float4 w = (m1 < M) ? *(const float4*)(A + (size_t)m1*K + (k0+ac)) : make_float4(0.f,0.f,0.f,0.f);
      As[ac+0][ar+64] = w.x; As[ac+1][ar+64] = w.y; As[ac+2][ar+64] = w.z; As[ac+3][ar+64] = w.w;
      int n0 = col0 + bc;
      float4 u0 = (n0 < Ncols) ? *(const float4*)(B + (size_t)(k0+br)*Ncols + n0) : make_float4(0.f,0.f,0.f,0.f);
      *(float4*)&Bs[br][bc] = u0;
      float4 u1 = (n0 < Ncols) ? *(const float4*)(B + (size_t)(k0+br+8)*Ncols + n0) : make_float4(0.f,0.f,0.f,0.f);
      *(float4*)&Bs[br+8][bc] = u1;
    }
    __syncthreads();
    #pragma unroll
    for (int kk = 0; kk < BK; kk++) {
      float a[8], b[8];
      *(float4*)(a)   = *(const float4*)&As[kk][tr];
      *(float4*)(a+4) = *(const float4*)&As[kk][tr+4];
      *(float4*)(b)   = *(const float4*)&Bs[kk][tc];
      *(float4*)(b+4) = *(const float4*)&Bs[kk][tc+4];
      #pragma unroll
      for (int i = 0; i < 8; i++)
        #pragma unroll
        for (int j = 0; j < 8; j++)
          acc[i][j] = fmaf(a[i], b[j], acc[i][j]);
    }
    __syncthreads();
  }

  if (EPI == 0) {
    #pragma unroll
    for (int i = 0; i < 8; i++) {
      int m = row0 + tr + i;
      if (m < M) {
        *(float4*)(C + (size_t)m*Ncols + col0+tc)   = *(float4*)&acc[i][0];
        *(float4*)(C + (size_t)m*Ncols + col0+tc+4) = *(float4*)&acc[i][4];
      }
    }
  } else {
    // scatter into h2 [2N, 392]: h2[m][n] = P[m][n] + CFW[c][392+n]  (n<392)
    //                            h2[N+m][n-392] = P[m][n] + CFW[c][n-392]  (n>=392)
    #pragma unroll
    for (int i = 0; i < 8; i++) {
      int m = row0 + tr + i;
      if (m >= M) continue;
      int c = cmax[m];
      const float* cf = CFW + (size_t)c * NB2;
      #pragma unroll
      for (int j = 0; j < 8; j++) {
        int n = col0 + tc + j;
        if (n >= NB2) continue;
        float v = acc[i][j];
        if (n < NCOL2) h2[(size_t)m*NCOL2 + n] = v + cf[NCOL2 + n];
        else           h2[(size_t)(NNODES + m)*NCOL2 + (n - NCOL2)] = v + cf[n - NCOL2];
      }
    }
  }
}

// ---------------- CSR build ----------------
__global__ void hist_kernel(const int* __restrict__ ei, int* __restrict__ counts) {
  int e = blockIdx.x*256 + threadIdx.x;
  if (e < NEDGES) atomicAdd(&counts[ei[NEDGES + e]], 1);
}

__global__ __launch_bounds__(1024) void scan_kernel(const int* __restrict__ counts,
                                                    int* __restrict__ rowptr, int* __restrict__ cursor) {
  __shared__ int part[1024];
  int t = threadIdx.x;
  const int CH = 20;                 // 1024*20 >= 20000
  int start = t*CH;
  int end = min(start+CH, NNODES);
  int sum = 0;
  for (int i = start; i < end; i++) sum += counts[i];
  part[t] = sum;
  __syncthreads();
  for (int off = 1; off < 1024; off <<= 1) {
    int v = part[t];
    int add = (t >= off) ? part[t-off] : 0;
    __syncthreads();
    part[t] = v + add;
    __syncthreads();
  }
  int run = part[t] - sum;           // exclusive prefix
  for (int i = start; i < end; i++) {
    rowptr[i] = run; cursor[i] = run;
    run += counts[i];
  }
  if (t == 1023) rowptr[NNODES] = part[1023];
}

__global__ void scatter_kernel(const int* __restrict__ ei, int* __restrict__ cursor, int* __restrict__ csr) {
  int e = blockIdx.x*256 + threadIdx.x;
  if (e < NEDGES) {
    int src = ei[e];
    int dst = ei[NEDGES + e];
    int pos = atomicAdd(&cursor[dst], 1);
    csr[pos] = src;
  }
}

// ---------------- conv1 attention logits: a_src/a_dst [N,8] ----------------
__global__ __launch_bounds__(256) void a1_kernel(
    const float* __restrict__ hpre, const float* __restrict__ atts, const float* __restrict__ attd,
    float* __restrict__ as1, float* __restrict__ ad1)
{
  int lane = threadIdx.x & 63;
  int i = blockIdx.x*4 + (threadIdx.x >> 6);
  const float* hp = hpre + (size_t)i*HC1 + lane*8;
  float4 h0 = *(const float4*)hp, h1 = *(const float4*)(hp+4);
  const float* ap = atts + lane*8; const float* dp = attd + lane*8;
  float4 a0 = *(const float4*)ap, a1v = *(const float4*)(ap+4);
  float4 d0 = *(const float4*)dp, d1v = *(const float4*)(dp+4);
  float ps = h0.x*a0.x + h0.y*a0.y + h0.z*a0.z + h0.w*a0.w
           + h1.x*a1v.x + h1.y*a1v.y + h1.z*a1v.z + h1.w*a1v.w;
  float pd = h0.x*d0.x + h0.y*d0.y + h0.z*d0.z + h0.w*d0.w
           + h1.x*d1v.x + h1.y*d1v.y + h1.z*d1v.z + h1.w*d1v.w;
  ps += __shfl_down(ps, 4, 8); ps += __shfl_down(ps, 2, 8); ps += __shfl_down(ps, 1, 8);
  pd += __shfl_down(pd, 4, 8); pd += __shfl_down(pd, 2, 8); pd += __shfl_down(pd, 1, 8);
  if ((lane & 7) == 0) {
    as1[i*8 + (lane >> 3)] = ps;
    ad1[i*8 + (lane >> 3)] = pd;
  }
}

// ---------------- conv1 aggregation + ELU: one wave per dst node ----------------
__global__ __launch_bounds__(256) void agg1_kernel(
    const float* __restrict__ hpre, const float* __restrict__ as1, const float* __restrict__ ad1,
    const int* __restrict__ rowptr, const int* __restrict__ csr, const float* __restrict__ b1,
    float* __restrict__ hout)
{
  int lane = threadIdx.x & 63;
  int i = blockIdx.x*4 + (threadIdx.x >> 6);
  int hd = lane >> 3;
  int rs = rowptr[i];
  int deg = rowptr[i+1] - rs;
  float adst[8], m[8], s[8], eself[8];
  #pragma unroll
  for (int h = 0; h < 8; h++) {
    adst[h] = ad1[i*8+h];
    eself[h] = lrelu(as1[i*8+h] + adst[h]);
    m[h] = eself[h];
    s[h] = 1.f;
  }
  for (int base = 0; base < deg; base += 64) {
    int j = base + lane;
    float e[8];
    if (j < deg) {
      int src = csr[rs+j];
      #pragma unroll
      for (int h = 0; h < 8; h++) e[h] = lrelu(as1[src*8+h] + adst[h]);
    } else {
      #pragma unroll
      for (int h = 0; h < 8; h++) e[h] = -1e30f;
    }
    #pragma unroll
    for (int h = 0; h < 8; h++) {
      float x = e[h];
      #pragma unroll
      for (int off = 32; off > 0; off >>= 1) x = fmaxf(x, __shfl_xor(x, off));
      float p = __expf(e[h] - x);
      #pragma unroll
      for (int off = 32; off > 0; off >>= 1) p += __shfl_xor(p, off);
      float nm = fmaxf(m[h], x);
      s[h] = s[h]*__expf(m[h]-nm) + p*__expf(x-nm);
      m[h] = nm;
    }
  }
  float msel = m[hd];
  float invs = 1.f / s[hd];
  float adsel = adst[hd];
  float acc[8];
  {
    float asf = __expf(eself[hd] - msel) * invs;
    const float* hp = hpre + (size_t)i*HC1 + lane*8;
    float4 v0 = *(const float4*)hp;
    float4 v1 = *(const float4*)(hp+4);
    acc[0]=asf*v0.x; acc[1]=asf*v0.y; acc[2]=asf*v0.z; acc[3]=asf*v0.w;
    acc[4]=asf*v1.x; acc[5]=asf*v1.y; acc[6]=asf*v1.z; acc[7]=asf*v1.w;
  }
  for (int j = 0; j < deg; j++) {
    int src = csr[rs+j];
    float al = __expf(lrelu(as1[src*8+hd] + adsel) - msel) * invs;
    const float* hp = hpre + (size_t)src*HC1 + lane*8;
    float4 v0 = *(const float4*)hp;
    float4 v1 = *(const float4*)(hp+4);
    acc[0] = fmaf(al, v0.x, acc[0]); acc[1] = fmaf(al, v0.y, acc[1]);
    acc[2] = fmaf(al, v0.z, acc[2]); acc[3] = fmaf(al, v0.w, acc[3]);
    acc[4] = fmaf(al, v1.x, acc[4]); acc[5] = fmaf(al, v1.y, acc[5]);
    acc[6] = fmaf(al, v1.z, acc[6]); acc[7] = fmaf(al, v1.w, acc[7]);
  }
  float* ho = hout + (size_t)i*HC1 + lane*8;
  #pragma unroll
  for (int k = 0; k < 8; k++) {
    float v = acc[k] + b1[lane*8 + k];
    ho[k] = v > 0.f ? v : __expf(v) - 1.f;   // ELU
  }
}

// ---------------- cluster stage ----------------
__global__ __launch_bounds__(256) void colsum_kernel(
    const float* __restrict__ cluster_id, const int* __restrict__ cidx, float* __restrict__ colsum)
{
  __shared__ float part[4][64];
  int tid = threadIdx.x; int q = tid >> 6, col = tid & 63;
  int start = blockIdx.x*313, end = min(start+313, NIDX);
  float acc = 0.f;
  for (int t = start + q; t < end; t += 4) {
    int node = cidx[t];
    acc += cluster_id[(size_t)node*NCLU + col];
  }
  part[q][col] = acc;
  __syncthreads();
  if (tid < 64) {
    float v = part[0][tid] + part[1][tid] + part[2][tid] + part[3][tid];
    atomicAdd(&colsum[tid], v);
  }
}

__global__ __launch_bounds__(256) void cf_kernel(
    const float* __restrict__ cluster_id, const int* __restrict__ cidx,
    const float* __restrict__ h, float* __restrict__ CFraw)
{
  int tid = threadIdx.x;
  int ch = blockIdx.y*64 + (tid & 63);
  int cb = blockIdx.x*16 + (tid >> 6)*4;
  int start = blockIdx.z*400, end = start + 400;   // 25*400 == NIDX
  float a0=0.f, a1=0.f, a2=0.f, a3=0.f;
  #pragma unroll 4
  for (int t = start; t < end; t++) {
    int node = cidx[t];
    float hv = h[(size_t)node*HC1 + ch];
    const float* cp = cluster_id + (size_t)node*NCLU + cb;
    a0 = fmaf(cp[0], hv, a0); a1 = fmaf(cp[1], hv, a1);
    a2 = fmaf(cp[2], hv, a2); a3 = fmaf(cp[3], hv, a3);
  }
  atomicAdd(&CFraw[(size_t)(cb+0)*HC1 + ch], a0);
  atomicAdd(&CFraw[(size_t)(cb+1)*HC1 + ch], a1);
  atomicAdd(&CFraw[(size_t)(cb+2)*HC1 + ch], a2);
  atomicAdd(&CFraw[(size_t)(cb+3)*HC1 + ch], a3);
}

__global__ __launch_bounds__(256) void argmax_kernel(const float* __restrict__ cluster_id, int* __restrict__ cmax)
{
  int lane = threadIdx.x & 63;
  int i = blockIdx.x*4 + (threadIdx.x >> 6);
  float v = cluster_id[(size_t)i*NCLU + lane];
  int idx = lane;
  #pragma unroll
  for (int off = 32; off > 0; off >>= 1) {
    float ov = __shfl_xor(v, off);
    int oi = __shfl_xor(idx, off);
    if (ov > v || (ov == v && oi < idx)) { v = ov; idx = oi; }  // first-max tie-break
  }
  if (lane == 0) cmax[i] = idx;
}

__global__ void packB2_kernel(const float* __restrict__ W2, float* __restrict__ B2) {
  int idx = blockIdx.x*256 + threadIdx.x;   // < 512*784
  int k = idx / NB2, j = idx - k*NB2;
  B2[idx] = (j < NCOL2) ? W2[(size_t)k*NCOL2 + j] : W2[(size_t)(512+k)*NCOL2 + (j - NCOL2)];
}

__global__ __launch_bounds__(256) void cfw_kernel(
    const float* __restrict__ CFraw, const float* __restrict__ colsum,
    const float* __restrict__ B2, float* __restrict__ CFW)
{
  int o = blockIdx.x*256 + threadIdx.x;     // < 64*784
  int c = o / NB2, j = o - c*NB2;
  float acc = 0.f;
  for (int k = 0; k < 512; k++) acc = fmaf(CFraw[(size_t)c*512 + k], B2[(size_t)k*NB2 + j], acc);
  CFW[o] = acc / colsum[c];
}

// ---------------- conv2 attention logits [2N,8] ----------------
__global__ __launch_bounds__(256) void a2_kernel(
    const float* __restrict__ h2, const float* __restrict__ atts, const float* __restrict__ attd,
    float* __restrict__ as2, float* __restrict__ ad2)
{
  __shared__ float rows[32*NCOL2];
  __shared__ float sa[NCOL2], sd[NCOL2];
  int tid = threadIdx.x;
  size_t base = (size_t)blockIdx.x * 32 * NCOL2;
  for (int idx = tid; idx < 32*NCOL2; idx += 256) rows[idx] = h2[base + idx];
  for (int idx = tid; idx < NCOL2; idx += 256) { sa[idx] = atts[idx]; sd[idx] = attd[idx]; }
  __syncthreads();
  int r = tid >> 3, hd = tid & 7;
  const float* rp = rows + r*NCOL2 + hd*OUT2;
  const float* ap = sa + hd*OUT2;
  const float* dp = sd + hd*OUT2;
  float ps = 0.f, pd = 0.f;
  #pragma unroll
  for (int j = 0; j < OUT2; j++) { float v = rp[j]; ps = fmaf(v, ap[j], ps); pd = fmaf(v, dp[j], pd); }
  int node = blockIdx.x*32 + r;
  as2[node*8 + hd] = ps;
  ad2[node*8 + hd] = pd;
}

// ---------------- conv2 aggregation + head-mean: one wave per dst node ----------------
__global__ __launch_bounds__(256) void agg2_kernel(
    const float* __restrict__ h2, const float* __restrict__ as2, const float* __restrict__ ad2,
    const int* __restrict__ rowptr, const int* __restrict__ csr, const float* __restrict__ b2,
    float* __restrict__ out)
{
  __shared__ float red[4][NCOL2];
  int lane = threadIdx.x & 63;
  int w = threadIdx.x >> 6;
  int u = blockIdx.x*4 + w;
  int bn = (u < NNODES) ? u : u - NNODES;
  int off = u - bn;                 // 0 or NNODES (doubled graph reuses CSR)
  int rs = rowptr[bn];
  int deg = rowptr[bn+1] - rs;
  float adst[8], m[8], s[8], eself[8];
  #pragma unroll
  for (int h = 0; h < 8; h++) {
    adst[h] = ad2[u*8+h];
    eself[h] = lrelu(as2[u*8+h] + adst[h]);
    m[h] = eself[h];
    s[h] = 1.f;
  }
  for (int base = 0; base < deg; base += 64) {
    int j = base + lane;
    float e[8];
    if (j < deg) {
      int src = csr[rs+j] + off;
      #pragma unroll
      for (int h = 0; h < 8; h++) e[h] = lrelu(as2[src*8+h] + adst[h]);
    } else {
      #pragma unroll
      for (int h = 0; h < 8; h++) e[h] = -1e30f;
    }
    #pragma unroll
    for (int h = 0; h < 8; h++) {
      float x = e[h];
      #pragma unroll
      for (int offx = 32; offx > 0; offx >>= 1) x = fmaxf(x, __shfl_xor(x, offx));
      float p = __expf(e[h] - x);
      #pragma unroll
      for (int offx = 32; offx > 0; offx >>= 1) p += __shfl_xor(p, offx);
      float nm = fmaxf(m[h], x);
      s[h] = s[h]*__expf(m[h]-nm) + p*__expf(x-nm);
      m[h] = nm;
    }
  }
  float inv[8], aself[8];
  #pragma unroll
  for (int h = 0; h < 8; h++) { inv[h] = 1.f / s[h]; aself[h] = __expf(eself[h]-m[h]) * inv[h]; }
  float acc[7];
  #pragma unroll
  for (int k = 0; k < 7; k++) {
    int c = lane + 64*k;
    acc[k] = 0.f;
    if (c < NCOL2) acc[k] = aself[c/OUT2] * h2[(size_t)u*NCOL2 + c];
  }
  for (int j = 0; j < deg; j++) {
    int src = csr[rs+j] + off;
    float al[8];
    #pragma unroll
    for (int h = 0; h < 8; h++) al[h] = __expf(lrelu(as2[src*8+h] + adst[h]) - m[h]) * inv[h];
    const float* hp = h2 + (size_t)src*NCOL2;
    #pragma unroll
    for (int k = 0; k < 7; k++) {
      int c = lane + 64*k;
      if (c < NCOL2) acc[k] = fmaf(al[c/OUT2], hp[c], acc[k]);
    }
  }
  #pragma unroll
  for (int k = 0; k < 7; k++) { int c = lane + 64*k; if (c < NCOL2) red[w][c] = acc[k]; }
  __syncthreads();
  if (lane < OUT2) {
    float t = 0.f;
    #pragma unroll
    for (int h = 0; h < 8; h++) t += red[w][h*OUT2 + lane];
    out[(size_t)u*OUT2 + lane] = 0.125f*t + b2[lane];   // mean over heads + bias
  }
}

// ---------------- launch ----------------
extern "C" void kernel_launch(void* const* d_in, const int* in_sizes, int n_in,
                              void* d_out, int out_size, void* d_ws, size_t ws_size,
                              hipStream_t stream)
{
  (void)in_sizes; (void)n_in; (void)out_size; (void)ws_size;
  const float* x     = (const float*)d_in[0];
  const int*   ei    = (const int*)d_in[1];
  const float* cid   = (const float*)d_in[2];
  const int*   cidx  = (const int*)d_in[3];
  const float* W1    = (const float*)d_in[4];
  const float* atts1 = (const float*)d_in[5];
  const float* attd1 = (const float*)d_in[6];
  const float* b1    = (const float*)d_in[7];
  const float* W2    = (const float*)d_in[8];
  const float* atts2 = (const float*)d_in[9];
  const float* attd2 = (const float*)d_in[10];
  const float* b2    = (const float*)d_in[11];
  float* out = (float*)d_out;

  char* ws = (char*)d_ws;
  size_t off = 0;
  auto alloc = [&](size_t b){ size_t r = off; off += (b + 255) & ~(size_t)255; return r; };
  size_t o_hpre = alloc((size_t)NNODES*HC1*4);
  size_t o_h    = alloc((size_t)NNODES*HC1*4);
  size_t o_h2   = alloc((size_t)2*NNODES*NCOL2*4);
  size_t o_B2   = alloc((size_t)512*NB2*4);
  size_t o_CFW  = alloc((size_t)NCLU*NB2*4);
  size_t o_as1  = alloc((size_t)NNODES*8*4);
  size_t o_ad1  = alloc((size_t)NNODES*8*4);
  size_t o_as2  = alloc((size_t)2*NNODES*8*4);
  size_t o_ad2  = alloc((size_t)2*NNODES*8*4);
  size_t o_rp   = alloc((size_t)(NNODES+1)*4);
  size_t o_cur  = alloc((size_t)NNODES*4);
  size_t o_csr  = alloc((size_t)NEDGES*4);
  size_t o_cmax = alloc((size_t)NNODES*4);
  size_t o_cnt  = alloc((size_t)NNODES*4);
  size_t o_csum = alloc(256 + (size_t)NCLU*HC1*4);   // colsum(64) then CFraw, contiguous for one memset

  float* hpre  = (float*)(ws + o_hpre);
  float* h     = (float*)(ws + o_h);
  float* h2    = (float*)(ws + o_h2);
  float* B2    = (float*)(ws + o_B2);
  float* CFW   = (float*)(ws + o_CFW);
  float* as1   = (float*)(ws + o_as1);
  float* ad1   = (float*)(ws + o_ad1);
  float* as2   = (float*)(ws + o_as2);
  float* ad2   = (float*)(ws + o_ad2);
  int*   rp    = (int*)(ws + o_rp);
  int*   cur   = (int*)(ws + o_cur);
  int*   csr   = (int*)(ws + o_csr);
  int*   cmax  = (int*)(ws + o_cmax);
  int*   cnt   = (int*)(ws + o_cnt);
  float* colsum= (float*)(ws + o_csum);
  float* CFraw = (float*)(ws + o_csum + 256);

  hipMemsetAsync(ws + o_cnt, 0, (size_t)NNODES*4, stream);
  hipMemsetAsync(ws + o_csum, 0, 256 + (size_t)NCLU*HC1*4, stream);

  // conv1 linear
  gemm_kernel<0><<<dim3(157,4), 256, 0, stream>>>(x, W1, hpre, NNODES, 512, nullptr, nullptr, nullptr);
  // CSR (shared by both convs; doubled graph has identical adjacency)
  hist_kernel<<<1250, 256, 0, stream>>>(ei, cnt);
  scan_kernel<<<1, 1024, 0, stream>>>(cnt, rp, cur);
  scatter_kernel<<<1250, 256, 0, stream>>>(ei, cur, csr);
  // conv1 attention + aggregation + ELU
  a1_kernel<<<5000, 256, 0, stream>>>(hpre, atts1, attd1, as1, ad1);
  agg1_kernel<<<5000, 256, 0, stream>>>(hpre, as1, ad1, rp, csr, b1, h);
  // cluster features
  colsum_kernel<<<32, 256, 0, stream>>>(cid, cidx, colsum);
  cf_kernel<<<dim3(4,8,25), 256, 0, stream>>>(cid, cidx, h, CFraw);
  argmax_kernel<<<5000, 256, 0, stream>>>(cid, cmax);
  packB2_kernel<<<1568, 256, 0, stream>>>(W2, B2);
  cfw_kernel<<<196, 256, 0, stream>>>(CFraw, colsum, B2, CFW);
  // conv2 linear (h @ [W2_top|W2_bot]) with fused x1-add + scatter into h2 [2N,392]
  gemm_kernel<1><<<dim3(157,7), 256, 0, stream>>>(h, B2, nullptr, NNODES, NB2, cmax, CFW, h2);
  // conv2 attention + aggregation + head-mean
  a2_kernel<<<1250, 256, 0, stream>>>(h2, atts2, attd2, as2, ad2);
  agg2_kernel<<<10000, 256, 0, stream>>>(h2, as2, ad2, rp, csr, b2, out);
}

// Round 2
// 881.299 us; speedup vs baseline: 1.2858x; 1.2858x over previous
//
#include <hip/hip_runtime.h>

#define NNODES 20000
#define NEDGES 320000
#define FIN    512
#define HC1    512      // H1*HID
#define NHEAD  8
#define OUT2   49
#define NCOL2  392      // NHEAD*OUT2
#define NB2    784      // 2*NCOL2
#define NCLU   64
#define NIDX   10000
#define NEG    0.2f

typedef unsigned short u16;
typedef short bf16x8 __attribute__((ext_vector_type(8)));
typedef float f32x4 __attribute__((ext_vector_type(4)));

static __device__ __forceinline__ float lrelu(float v){ return v > 0.f ? v : NEG*v; }

static __device__ __forceinline__ u16 f2bf_hi(float f, float& rem) {
  union { float f; unsigned u; } c; c.f = f;
  unsigned hb = c.u & 0xFFFF0000u;
  union { unsigned u; float f; } d; d.u = hb;
  rem = f - d.f;                       // exact (Sterbenz)
  return (u16)(hb >> 16);
}
static __device__ __forceinline__ u16 f2bf(float f) {
  union { float f; unsigned u; } c; c.f = f;
  return (u16)(c.u >> 16);
}
static __device__ __forceinline__ float bf2f(u16 u) {
  union { unsigned u; float f; } c; c.u = ((unsigned)u) << 16;
  return c.f;
}

// ---------------- input split kernels ----------------
__global__ void split4_kernel(const float* __restrict__ src, u16* __restrict__ hi, u16* __restrict__ lo) {
  int i = blockIdx.x*256 + threadIdx.x;        // grid sized exactly
  float4 v = ((const float4*)src)[i];
  float r0,r1,r2,r3;
  ushort4 h, l;
  h.x = f2bf_hi(v.x, r0); h.y = f2bf_hi(v.y, r1); h.z = f2bf_hi(v.z, r2); h.w = f2bf_hi(v.w, r3);
  l.x = f2bf(r0); l.y = f2bf(r1); l.z = f2bf(r2); l.w = f2bf(r3);
  ((ushort4*)hi)[i] = h;
  ((ushort4*)lo)[i] = l;
}

__global__ void tw1_kernel(const float* __restrict__ W1, u16* __restrict__ Th, u16* __restrict__ Tl) {
  int idx = blockIdx.x*256 + threadIdx.x;      // < 512*512
  int k = idx >> 9, j = idx & 511;
  float rem; u16 hi = f2bf_hi(W1[idx], rem);
  Th[(size_t)j*512 + k] = hi;
  Tl[(size_t)j*512 + k] = f2bf(rem);
}

__global__ void tb2_kernel(const float* __restrict__ W2, u16* __restrict__ Th, u16* __restrict__ Tl) {
  int idx = blockIdx.x*256 + threadIdx.x;      // < 512*784
  int k = idx / NB2, j = idx - k*NB2;
  float v = (j < NCOL2) ? W2[(size_t)k*NCOL2 + j] : W2[(size_t)(512+k)*NCOL2 + (j - NCOL2)];
  float rem; u16 hi = f2bf_hi(v, rem);
  Th[(size_t)j*512 + k] = hi;
  Tl[(size_t)j*512 + k] = f2bf(rem);
}

// ---------------- split-bf16 MFMA GEMM: C[M,N] = A[M,512] @ B[512,N] ----------------
// A given as Ah/Al [M,512] bf16 row-major; B given as Bh/Bl [N,512] bf16 (transposed).
// C ~= Ah Bh + Ah Bl + Al Bh  (fp32 MFMA accum; input error ~2^-16 relative)
template<int EPI>
__global__ __launch_bounds__(256) void gemm_mfma(
    const u16* __restrict__ Ah, const u16* __restrict__ Al,
    const u16* __restrict__ Bh, const u16* __restrict__ Bl,
    float* __restrict__ C, int M, int Ncols,
    const int* __restrict__ cmax, const float* __restrict__ CFW, float* __restrict__ h2)
{
  __shared__ __align__(16) u16 As[2][128][40];   // rows padded to 80B: b128 frag reads conflict-free
  __shared__ __align__(16) u16 Bs[2][128][40];
  int tid = threadIdx.x;
  int row0 = blockIdx.x * 128;
  int col0 = blockIdx.y * 128;
  int lane = tid & 63;
  int wid = tid >> 6;
  int wr = (wid >> 1) * 64;            // wave's 64x64 sub-tile
  int wc = (wid & 1) * 64;
  int l16 = lane & 15;
  int q = lane >> 4;
  f32x4 acc[4][4];
  #pragma unroll
  for (int i = 0; i < 4; i++)
    #pragma unroll
    for (int j = 0; j < 4; j++)
      acc[i][j] = (f32x4){0.f, 0.f, 0.f, 0.f};

  int srow = tid >> 2;                 // 0..63
  int sq = tid & 3;                    // 16B chunk within 64B row-chunk
  const uint4 z4 = make_uint4(0,0,0,0);

  for (int k0 = 0; k0 < 512; k0 += 32) {
    #pragma unroll
    for (int part = 0; part < 2; part++) {
      int r = part*64 + srow;
      int gm = row0 + r;
      uint4 vh = z4, vl = z4;
      if (gm < M) {
        vh = *(const uint4*)(Ah + (size_t)gm*512 + k0 + sq*8);
        vl = *(const uint4*)(Al + (size_t)gm*512 + k0 + sq*8);
      }
      *(uint4*)&As[0][r][sq*8] = vh;
      *(uint4*)&As[1][r][sq*8] = vl;
      int gn = col0 + r;
      uint4 wh = z4, wl = z4;
      if (gn < Ncols) {
        wh = *(const uint4*)(Bh + (size_t)gn*512 + k0 + sq*8);
        wl = *(const uint4*)(Bl + (size_t)gn*512 + k0 + sq*8);
      }
      *(uint4*)&Bs[0][r][sq*8] = wh;
      *(uint4*)&Bs[1][r][sq*8] = wl;
    }
    __syncthreads();
    bf16x8 ah[4], al[4], bh[4], bl[4];
    #pragma unroll
    for (int i = 0; i < 4; i++) {
      ah[i] = *(const bf16x8*)&As[0][wr + i*16 + l16][q*8];
      al[i] = *(const bf16x8*)&As[1][wr + i*16 + l16][q*8];
      bh[i] = *(const bf16x8*)&Bs[0][wc + i*16 + l16][q*8];
      bl[i] = *(const bf16x8*)&Bs[1][wc + i*16 + l16][q*8];
    }
    #pragma unroll
    for (int i = 0; i < 4; i++)
      #pragma unroll
      for (int j = 0; j < 4; j++) {
        acc[i][j] = __builtin_amdgcn_mfma_f32_16x16x32_bf16(ah[i], bh[j], acc[i][j], 0, 0, 0);
        acc[i][j] = __builtin_amdgcn_mfma_f32_16x16x32_bf16(ah[i], bl[j], acc[i][j], 0, 0, 0);
        acc[i][j] = __builtin_amdgcn_mfma_f32_16x16x32_bf16(al[i], bh[j], acc[i][j], 0, 0, 0);
      }
    __syncthreads();
  }

  if (EPI == 0) {
    #pragma unroll
    for (int i = 0; i < 4; i++) {
      #pragma unroll
      for (int r = 0; r < 4; r++) {
        int m = row0 + wr + i*16 + q*4 + r;
        if (m < M) {
          #pragma unroll
          for (int j = 0; j < 4; j++)
            C[(size_t)m*Ncols + col0 + wc + j*16 + l16] = acc[i][j][r];
        }
      }
    }
  } else {
    // scatter into h2 [2N,392] with fused cluster-feature add
    #pragma unroll
    for (int i = 0; i < 4; i++) {
      #pragma unroll
      for (int r = 0; r < 4; r++) {
        int m = row0 + wr + i*16 + q*4 + r;
        if (m >= M) continue;
        int c = cmax[m];
        const float* cf = CFW + (size_t)c * NB2;
        #pragma unroll
        for (int j = 0; j < 4; j++) {
          int n = col0 + wc + j*16 + l16;
          if (n >= NB2) continue;
          float v = acc[i][j][r];
          if (n < NCOL2) h2[(size_t)m*NCOL2 + n] = v + cf[NCOL2 + n];
          else           h2[(size_t)(NNODES + m)*NCOL2 + (n - NCOL2)] = v + cf[n - NCOL2];
        }
      }
    }
  }
}

// ---------------- CSR build ----------------
__global__ void hist_kernel(const int* __restrict__ ei, int* __restrict__ counts) {
  int e = blockIdx.x*256 + threadIdx.x;
  if (e < NEDGES) atomicAdd(&counts[ei[NEDGES + e]], 1);
}

__global__ __launch_bounds__(1024) void scan_kernel(const int* __restrict__ counts,
                                                    int* __restrict__ rowptr, int* __restrict__ cursor) {
  __shared__ int part[1024];
  int t = threadIdx.x;
  const int CH = 20;
  int start = t*CH;
  int end = min(start+CH, NNODES);
  int sum = 0;
  for (int i = start; i < end; i++) sum += counts[i];
  part[t] = sum;
  __syncthreads();
  for (int off = 1; off < 1024; off <<= 1) {
    int v = part[t];
    int add = (t >= off) ? part[t-off] : 0;
    __syncthreads();
    part[t] = v + add;
    __syncthreads();
  }
  int run = part[t] - sum;
  for (int i = start; i < end; i++) {
    rowptr[i] = run; cursor[i] = run;
    run += counts[i];
  }
  if (t == 1023) rowptr[NNODES] = part[1023];
}

__global__ void scatter_kernel(const int* __restrict__ ei, int* __restrict__ cursor, int* __restrict__ csr) {
  int e = blockIdx.x*256 + threadIdx.x;
  if (e < NEDGES) {
    int src = ei[e];
    int dst = ei[NEDGES + e];
    int pos = atomicAdd(&cursor[dst], 1);
    csr[pos] = src;
  }
}

// ---------------- conv1 attention logits ----------------
__global__ __launch_bounds__(256) void a1_kernel(
    const float* __restrict__ hpre, const float* __restrict__ atts, const float* __restrict__ attd,
    float* __restrict__ as1, float* __restrict__ ad1)
{
  int lane = threadIdx.x & 63;
  int i = blockIdx.x*4 + (threadIdx.x >> 6);
  const float* hp = hpre + (size_t)i*HC1 + lane*8;
  float4 h0 = *(const float4*)hp, h1 = *(const float4*)(hp+4);
  const float* ap = atts + lane*8; const float* dp = attd + lane*8;
  float4 a0 = *(const float4*)ap, a1v = *(const float4*)(ap+4);
  float4 d0 = *(const float4*)dp, d1v = *(const float4*)(dp+4);
  float ps = h0.x*a0.x + h0.y*a0.y + h0.z*a0.z + h0.w*a0.w
           + h1.x*a1v.x + h1.y*a1v.y + h1.z*a1v.z + h1.w*a1v.w;
  float pd = h0.x*d0.x + h0.y*d0.y + h0.z*d0.z + h0.w*d0.w
           + h1.x*d1v.x + h1.y*d1v.y + h1.z*d1v.z + h1.w*d1v.w;
  ps += __shfl_down(ps, 4, 8); ps += __shfl_down(ps, 2, 8); ps += __shfl_down(ps, 1, 8);
  pd += __shfl_down(pd, 4, 8); pd += __shfl_down(pd, 2, 8); pd += __shfl_down(pd, 1, 8);
  if ((lane & 7) == 0) {
    as1[i*8 + (lane >> 3)] = ps;
    ad1[i*8 + (lane >> 3)] = pd;
  }
}

// ---------------- conv1 aggregation + ELU -> split bf16 h ----------------
__global__ __launch_bounds__(256) void agg1_kernel(
    const float* __restrict__ hpre, const float* __restrict__ as1, const float* __restrict__ ad1,
    const int* __restrict__ rowptr, const int* __restrict__ csr, const float* __restrict__ b1,
    u16* __restrict__ hh, u16* __restrict__ hl)
{
  int lane = threadIdx.x & 63;
  int i = blockIdx.x*4 + (threadIdx.x >> 6);
  int hd = lane >> 3;
  int rs = rowptr[i];
  int deg = rowptr[i+1] - rs;
  float adst[8], m[8], s[8], eself[8];
  #pragma unroll
  for (int h = 0; h < 8; h++) {
    adst[h] = ad1[i*8+h];
    eself[h] = lrelu(as1[i*8+h] + adst[h]);
    m[h] = eself[h];
    s[h] = 1.f;
  }
  for (int base = 0; base < deg; base += 64) {
    int j = base + lane;
    float e[8];
    if (j < deg) {
      int src = csr[rs+j];
      #pragma unroll
      for (int h = 0; h < 8; h++) e[h] = lrelu(as1[src*8+h] + adst[h]);
    } else {
      #pragma unroll
      for (int h = 0; h < 8; h++) e[h] = -1e30f;
    }
    #pragma unroll
    for (int h = 0; h < 8; h++) {
      float x = e[h];
      #pragma unroll
      for (int off = 32; off > 0; off >>= 1) x = fmaxf(x, __shfl_xor(x, off));
      float p = __expf(e[h] - x);
      #pragma unroll
      for (int off = 32; off > 0; off >>= 1) p += __shfl_xor(p, off);
      float nm = fmaxf(m[h], x);
      s[h] = s[h]*__expf(m[h]-nm) + p*__expf(x-nm);
      m[h] = nm;
    }
  }
  float msel = m[hd];
  float invs = 1.f / s[hd];
  float adsel = adst[hd];
  float acc[8];
  {
    float asf = __expf(eself[hd] - msel) * invs;
    const float* hp = hpre + (size_t)i*HC1 + lane*8;
    float4 v0 = *(const float4*)hp;
    float4 v1 = *(const float4*)(hp+4);
    acc[0]=asf*v0.x; acc[1]=asf*v0.y; acc[2]=asf*v0.z; acc[3]=asf*v0.w;
    acc[4]=asf*v1.x; acc[5]=asf*v1.y; acc[6]=asf*v1.z; acc[7]=asf*v1.w;
  }
  int j = 0;
  for (; j + 1 < deg; j += 2) {
    int s0 = csr[rs+j], s1 = csr[rs+j+1];
    float al0 = __expf(lrelu(as1[s0*8+hd] + adsel) - msel) * invs;
    float al1 = __expf(lrelu(as1[s1*8+hd] + adsel) - msel) * invs;
    const float* p0 = hpre + (size_t)s0*HC1 + lane*8;
    const float* p1 = hpre + (size_t)s1*HC1 + lane*8;
    float4 a0 = *(const float4*)p0, a1v = *(const float4*)(p0+4);
    float4 c0 = *(const float4*)p1, c1v = *(const float4*)(p1+4);
    acc[0] = fmaf(al0, a0.x, acc[0]); acc[1] = fmaf(al0, a0.y, acc[1]);
    acc[2] = fmaf(al0, a0.z, acc[2]); acc[3] = fmaf(al0, a0.w, acc[3]);
    acc[4] = fmaf(al0, a1v.x, acc[4]); acc[5] = fmaf(al0, a1v.y, acc[5]);
    acc[6] = fmaf(al0, a1v.z, acc[6]); acc[7] = fmaf(al0, a1v.w, acc[7]);
    acc[0] = fmaf(al1, c0.x, acc[0]); acc[1] = fmaf(al1, c0.y, acc[1]);
    acc[2] = fmaf(al1, c0.z, acc[2]); acc[3] = fmaf(al1, c0.w, acc[3]);
    acc[4] = fmaf(al1, c1v.x, acc[4]); acc[5] = fmaf(al1, c1v.y, acc[5]);
    acc[6] = fmaf(al1, c1v.z, acc[6]); acc[7] = fmaf(al1, c1v.w, acc[7]);
  }
  if (j < deg) {
    int s0 = csr[rs+j];
    float al0 = __expf(lrelu(as1[s0*8+hd] + adsel) - msel) * invs;
    const float* p0 = hpre + (size_t)s0*HC1 + lane*8;
    float4 a0 = *(const float4*)p0, a1v = *(const float4*)(p0+4);
    acc[0] = fmaf(al0, a0.x, acc[0]); acc[1] = fmaf(al0, a0.y, acc[1]);
    acc[2] = fmaf(al0, a0.z, acc[2]); acc[3] = fmaf(al0, a0.w, acc[3]);
    acc[4] = fmaf(al0, a1v.x, acc[4]); acc[5] = fmaf(al0, a1v.y, acc[5]);
    acc[6] = fmaf(al0, a1v.z, acc[6]); acc[7] = fmaf(al0, a1v.w, acc[7]);
  }
  u16 hh8[8], hl8[8];
  #pragma unroll
  for (int k = 0; k < 8; k++) {
    float v = acc[k] + b1[lane*8 + k];
    v = v > 0.f ? v : __expf(v) - 1.f;    // ELU
    float rem; hh8[k] = f2bf_hi(v, rem); hl8[k] = f2bf(rem);
  }
  size_t base = (size_t)i*HC1 + lane*8;
  *(ushort4*)(hh + base)     = make_ushort4(hh8[0],hh8[1],hh8[2],hh8[3]);
  *(ushort4*)(hh + base + 4) = make_ushort4(hh8[4],hh8[5],hh8[6],hh8[7]);
  *(ushort4*)(hl + base)     = make_ushort4(hl8[0],hl8[1],hl8[2],hl8[3]);
  *(ushort4*)(hl + base + 4) = make_ushort4(hl8[4],hl8[5],hl8[6],hl8[7]);
}

// ---------------- cluster stage ----------------
__global__ __launch_bounds__(256) void colsum_kernel(
    const float* __restrict__ cluster_id, const int* __restrict__ cidx, float* __restrict__ colsum)
{
  __shared__ float part[4][64];
  int tid = threadIdx.x; int q = tid >> 6, col = tid & 63;
  int start = blockIdx.x*313, end = min(start+313, NIDX);
  float acc = 0.f;
  for (int t = start + q; t < end; t += 4) {
    int node = cidx[t];
    acc += cluster_id[(size_t)node*NCLU + col];
  }
  part[q][col] = acc;
  __syncthreads();
  if (tid < 64) {
    float v = part[0][tid] + part[1][tid] + part[2][tid] + part[3][tid];
    atomicAdd(&colsum[tid], v);
  }
}

__global__ __launch_bounds__(256) void cf_kernel(
    const float* __restrict__ cluster_id, const int* __restrict__ cidx,
    const u16* __restrict__ hh, const u16* __restrict__ hl, float* __restrict__ CFraw)
{
  int tid = threadIdx.x;
  int ch = blockIdx.y*64 + (tid & 63);
  int cb = blockIdx.x*16 + (tid >> 6)*4;
  int start = blockIdx.z*400, end = start + 400;
  float a0=0.f, a1=0.f, a2=0.f, a3=0.f;
  #pragma unroll 4
  for (int t = start; t < end; t++) {
    int node = cidx[t];
    size_t idx = (size_t)node*HC1 + ch;
    float hv = bf2f(hh[idx]) + bf2f(hl[idx]);
    const float* cp = cluster_id + (size_t)node*NCLU + cb;
    a0 = fmaf(cp[0], hv, a0); a1 = fmaf(cp[1], hv, a1);
    a2 = fmaf(cp[2], hv, a2); a3 = fmaf(cp[3], hv, a3);
  }
  atomicAdd(&CFraw[(size_t)(cb+0)*HC1 + ch], a0);
  atomicAdd(&CFraw[(size_t)(cb+1)*HC1 + ch], a1);
  atomicAdd(&CFraw[(size_t)(cb+2)*HC1 + ch], a2);
  atomicAdd(&CFraw[(size_t)(cb+3)*HC1 + ch], a3);
}

__global__ __launch_bounds__(256) void argmax_kernel(const float* __restrict__ cluster_id, int* __restrict__ cmax)
{
  int lane = threadIdx.x & 63;
  int i = blockIdx.x*4 + (threadIdx.x >> 6);
  float v = cluster_id[(size_t)i*NCLU + lane];
  int idx = lane;
  #pragma unroll
  for (int off = 32; off > 0; off >>= 1) {
    float ov = __shfl_xor(v, off);
    int oi = __shfl_xor(idx, off);
    if (ov > v || (ov == v && oi < idx)) { v = ov; idx = oi; }
  }
  if (lane == 0) cmax[i] = idx;
}

__global__ __launch_bounds__(256) void cfw_kernel(
    const float* __restrict__ CFraw, const float* __restrict__ colsum,
    const float* __restrict__ W2, float* __restrict__ CFW)
{
  int o = blockIdx.x*256 + threadIdx.x;     // < 64*784
  int c = o / NB2, j = o - c*NB2;
  const float* src = (j < NCOL2) ? (W2 + j) : (W2 + (size_t)512*NCOL2 + (j - NCOL2));
  float acc = 0.f;
  for (int k = 0; k < 512; k++) acc = fmaf(CFraw[(size_t)c*512 + k], src[(size_t)k*NCOL2], acc);
  CFW[o] = acc / colsum[c];
}

// ---------------- conv2 attention logits ----------------
__global__ __launch_bounds__(256) void a2_kernel(
    const float* __restrict__ h2, const float* __restrict__ atts, const float* __restrict__ attd,
    float* __restrict__ as2, float* __restrict__ ad2)
{
  __shared__ float rows[32*NCOL2];
  __shared__ float sa[NCOL2], sd[NCOL2];
  int tid = threadIdx.x;
  size_t base = (size_t)blockIdx.x * 32 * NCOL2;
  for (int idx = tid; idx < 32*NCOL2; idx += 256) rows[idx] = h2[base + idx];
  for (int idx = tid; idx < NCOL2; idx += 256) { sa[idx] = atts[idx]; sd[idx] = attd[idx]; }
  __syncthreads();
  int r = tid >> 3, hd = tid & 7;
  const float* rp = rows + r*NCOL2 + hd*OUT2;
  const float* ap = sa + hd*OUT2;
  const float* dp = sd + hd*OUT2;
  float ps = 0.f, pd = 0.f;
  #pragma unroll
  for (int j = 0; j < OUT2; j++) { float v = rp[j]; ps = fmaf(v, ap[j], ps); pd = fmaf(v, dp[j], pd); }
  int node = blockIdx.x*32 + r;
  as2[node*8 + hd] = ps;
  ad2[node*8 + hd] = pd;
}

// ---------------- conv2 aggregation + head-mean ----------------
__global__ __launch_bounds__(256) void agg2_kernel(
    const float* __restrict__ h2, const float* __restrict__ as2, const float* __restrict__ ad2,
    const int* __restrict__ rowptr, const int* __restrict__ csr, const float* __restrict__ b2,
    float* __restrict__ out)
{
  __shared__ float red[4][NCOL2];
  int lane = threadIdx.x & 63;
  int w = threadIdx.x >> 6;
  int u = blockIdx.x*4 + w;
  int bn = (u < NNODES) ? u : u - NNODES;
  int off = u - bn;
  int rs = rowptr[bn];
  int deg = rowptr[bn+1] - rs;
  float adst[8], m[8], s[8], eself[8];
  #pragma unroll
  for (int h = 0; h < 8; h++) {
    adst[h] = ad2[u*8+h];
    eself[h] = lrelu(as2[u*8+h] + adst[h]);
    m[h] = eself[h];
    s[h] = 1.f;
  }
  for (int base = 0; base < deg; base += 64) {
    int j = base + lane;
    float e[8];
    if (j < deg) {
      int src = csr[rs+j] + off;
      #pragma unroll
      for (int h = 0; h < 8; h++) e[h] = lrelu(as2[src*8+h] + adst[h]);
    } else {
      #pragma unroll
      for (int h = 0; h < 8; h++) e[h] = -1e30f;
    }
    #pragma unroll
    for (int h = 0; h < 8; h++) {
      float x = e[h];
      #pragma unroll
      for (int offx = 32; offx > 0; offx >>= 1) x = fmaxf(x, __shfl_xor(x, offx));
      float p = __expf(e[h] - x);
      #pragma unroll
      for (int offx = 32; offx > 0; offx >>= 1) p += __shfl_xor(p, offx);
      float nm = fmaxf(m[h], x);
      s[h] = s[h]*__expf(m[h]-nm) + p*__expf(x-nm);
      m[h] = nm;
    }
  }
  float inv[8], aself[8];
  #pragma unroll
  for (int h = 0; h < 8; h++) { inv[h] = 1.f / s[h]; aself[h] = __expf(eself[h]-m[h]) * inv[h]; }
  float acc[7];
  #pragma unroll
  for (int k = 0; k < 7; k++) {
    int c = lane + 64*k;
    acc[k] = 0.f;
    if (c < NCOL2) acc[k] = aself[c/OUT2] * h2[(size_t)u*NCOL2 + c];
  }
  int j = 0;
  for (; j + 1 < deg; j += 2) {
    int s0 = csr[rs+j] + off, s1 = csr[rs+j+1] + off;
    float al0[8], al1[8];
    #pragma unroll
    for (int h = 0; h < 8; h++) {
      al0[h] = __expf(lrelu(as2[s0*8+h] + adst[h]) - m[h]) * inv[h];
      al1[h] = __expf(lrelu(as2[s1*8+h] + adst[h]) - m[h]) * inv[h];
    }
    const float* p0 = h2 + (size_t)s0*NCOL2;
    const float* p1 = h2 + (size_t)s1*NCOL2;
    #pragma unroll
    for (int k = 0; k < 7; k++) {
      int c = lane + 64*k;
      if (c < NCOL2) {
        acc[k] = fmaf(al0[c/OUT2], p0[c], acc[k]);
        acc[k] = fmaf(al1[c/OUT2], p1[c], acc[k]);
      }
    }
  }
  if (j < deg) {
    int s0 = csr[rs+j] + off;
    float al0[8];
    #pragma unroll
    for (int h = 0; h < 8; h++) al0[h] = __expf(lrelu(as2[s0*8+h] + adst[h]) - m[h]) * inv[h];
    const float* p0 = h2 + (size_t)s0*NCOL2;
    #pragma unroll
    for (int k = 0; k < 7; k++) {
      int c = lane + 64*k;
      if (c < NCOL2) acc[k] = fmaf(al0[c/OUT2], p0[c], acc[k]);
    }
  }
  #pragma unroll
  for (int k = 0; k < 7; k++) { int c = lane + 64*k; if (c < NCOL2) red[w][c] = acc[k]; }
  __syncthreads();
  if (lane < OUT2) {
    float t = 0.f;
    #pragma unroll
    for (int h = 0; h < 8; h++) t += red[w][h*OUT2 + lane];
    out[(size_t)u*OUT2 + lane] = 0.125f*t + b2[lane];
  }
}

// ---------------- launch ----------------
extern "C" void kernel_launch(void* const* d_in, const int* in_sizes, int n_in,
                              void* d_out, int out_size, void* d_ws, size_t ws_size,
                              hipStream_t stream)
{
  (void)in_sizes; (void)n_in; (void)out_size; (void)ws_size;
  const float* x     = (const float*)d_in[0];
  const int*   ei    = (const int*)d_in[1];
  const float* cid   = (const float*)d_in[2];
  const int*   cidx  = (const int*)d_in[3];
  const float* W1    = (const float*)d_in[4];
  const float* atts1 = (const float*)d_in[5];
  const float* attd1 = (const float*)d_in[6];
  const float* b1    = (const float*)d_in[7];
  const float* W2    = (const float*)d_in[8];
  const float* atts2 = (const float*)d_in[9];
  const float* attd2 = (const float*)d_in[10];
  const float* b2    = (const float*)d_in[11];
  float* out = (float*)d_out;

  char* ws = (char*)d_ws;
  size_t off = 0;
  auto alloc = [&](size_t b){ size_t r = off; off += (b + 255) & ~(size_t)255; return r; };
  size_t o_hpre = alloc((size_t)NNODES*HC1*4);
  size_t o_h2   = alloc((size_t)2*NNODES*NCOL2*4);
  size_t o_xh   = alloc((size_t)NNODES*FIN*2);
  size_t o_xl   = alloc((size_t)NNODES*FIN*2);
  size_t o_hh   = alloc((size_t)NNODES*HC1*2);
  size_t o_hl   = alloc((size_t)NNODES*HC1*2);
  size_t o_w1h  = alloc((size_t)512*512*2);
  size_t o_w1l  = alloc((size_t)512*512*2);
  size_t o_b2h  = alloc((size_t)NB2*512*2);
  size_t o_b2l  = alloc((size_t)NB2*512*2);
  size_t o_CFW  = alloc((size_t)NCLU*NB2*4);
  size_t o_as1  = alloc((size_t)NNODES*8*4);
  size_t o_ad1  = alloc((size_t)NNODES*8*4);
  size_t o_as2  = alloc((size_t)2*NNODES*8*4);
  size_t o_ad2  = alloc((size_t)2*NNODES*8*4);
  size_t o_rp   = alloc((size_t)(NNODES+1)*4);
  size_t o_cur  = alloc((size_t)NNODES*4);
  size_t o_csr  = alloc((size_t)NEDGES*4);
  size_t o_cmax = alloc((size_t)NNODES*4);
  size_t o_cnt  = alloc((size_t)NNODES*4);
  size_t o_csum = alloc(256 + (size_t)NCLU*HC1*4);

  float* hpre  = (float*)(ws + o_hpre);
  float* h2    = (float*)(ws + o_h2);
  u16*   xh    = (u16*)(ws + o_xh);
  u16*   xl    = (u16*)(ws + o_xl);
  u16*   hh    = (u16*)(ws + o_hh);
  u16*   hl    = (u16*)(ws + o_hl);
  u16*   w1h   = (u16*)(ws + o_w1h);
  u16*   w1l   = (u16*)(ws + o_w1l);
  u16*   b2h   = (u16*)(ws + o_b2h);
  u16*   b2l   = (u16*)(ws + o_b2l);
  float* CFW   = (float*)(ws + o_CFW);
  float* as1   = (float*)(ws + o_as1);
  float* ad1   = (float*)(ws + o_ad1);
  float* as2   = (float*)(ws + o_as2);
  float* ad2   = (float*)(ws + o_ad2);
  int*   rp    = (int*)(ws + o_rp);
  int*   cur   = (int*)(ws + o_cur);
  int*   csr   = (int*)(ws + o_csr);
  int*   cmax  = (int*)(ws + o_cmax);
  int*   cnt   = (int*)(ws + o_cnt);
  float* colsum= (float*)(ws + o_csum);
  float* CFraw = (float*)(ws + o_csum + 256);

  hipMemsetAsync(ws + o_cnt, 0, (size_t)NNODES*4, stream);
  hipMemsetAsync(ws + o_csum, 0, 256 + (size_t)NCLU*HC1*4, stream);

  // input splits
  split4_kernel<<<NNODES*FIN/4/256, 256, 0, stream>>>(x, xh, xl);
  tw1_kernel<<<1024, 256, 0, stream>>>(W1, w1h, w1l);
  // CSR (shared by both convs)
  hist_kernel<<<1250, 256, 0, stream>>>(ei, cnt);
  scan_kernel<<<1, 1024, 0, stream>>>(cnt, rp, cur);
  scatter_kernel<<<1250, 256, 0, stream>>>(ei, cur, csr);
  // conv1 linear (MFMA split-bf16)
  gemm_mfma<0><<<dim3(157,4), 256, 0, stream>>>(xh, xl, w1h, w1l, hpre, NNODES, 512, nullptr, nullptr, nullptr);
  // conv1 attention + aggregation + ELU (emits split-bf16 h)
  a1_kernel<<<5000, 256, 0, stream>>>(hpre, atts1, attd1, as1, ad1);
  agg1_kernel<<<5000, 256, 0, stream>>>(hpre, as1, ad1, rp, csr, b1, hh, hl);
  // cluster features
  tb2_kernel<<<1568, 256, 0, stream>>>(W2, b2h, b2l);
  colsum_kernel<<<32, 256, 0, stream>>>(cid, cidx, colsum);
  cf_kernel<<<dim3(4,8,25), 256, 0, stream>>>(cid, cidx, hh, hl, CFraw);
  argmax_kernel<<<5000, 256, 0, stream>>>(cid, cmax);
  cfw_kernel<<<196, 256, 0, stream>>>(CFraw, colsum, W2, CFW);
  // conv2 linear (MFMA split-bf16) with fused x1-add + scatter into h2 [2N,392]
  gemm_mfma<1><<<dim3(157,7), 256, 0, stream>>>(hh, hl, b2h, b2l, nullptr, NNODES, NB2, cmax, CFW, h2);
  // conv2 attention + aggregation + head-mean
  a2_kernel<<<1250, 256, 0, stream>>>(h2, atts2, attd2, as2, ad2);
  agg2_kernel<<<10000, 256, 0, stream>>>(h2, as2, ad2, rp, csr, b2, out);
}

// Round 3
// 833.151 us; speedup vs baseline: 1.3601x; 1.0578x over previous
//
#include <hip/hip_runtime.h>

#define NNODES 20000
#define NEDGES 320000
#define FIN    512
#define HC1    512      // H1*HID
#define NHEAD  8
#define OUT2   49
#define NCOL2  392      // NHEAD*OUT2
#define NB2    784      // 2*NCOL2
#define NCLU   64
#define NIDX   10000
#define NEG    0.2f

typedef unsigned short u16;
typedef short bf16x8 __attribute__((ext_vector_type(8)));
typedef float f32x4 __attribute__((ext_vector_type(4)));

static __device__ __forceinline__ float lrelu(float v){ return v > 0.f ? v : NEG*v; }

static __device__ __forceinline__ u16 f2bf_hi(float f, float& rem) {
  union { float f; unsigned u; } c; c.f = f;
  unsigned hb = c.u & 0xFFFF0000u;
  union { unsigned u; float f; } d; d.u = hb;
  rem = f - d.f;                       // exact
  return (u16)(hb >> 16);
}
static __device__ __forceinline__ u16 f2bf(float f) {
  union { float f; unsigned u; } c; c.f = f;
  return (u16)(c.u >> 16);
}
static __device__ __forceinline__ float bf2f(u16 u) {
  union { unsigned u; float f; } c; c.u = ((unsigned)u) << 16;
  return c.f;
}

// ---------------- input split kernels ----------------
__global__ void split4_kernel(const float* __restrict__ src, u16* __restrict__ hi, u16* __restrict__ lo) {
  int i = blockIdx.x*256 + threadIdx.x;
  float4 v = ((const float4*)src)[i];
  float r0,r1,r2,r3;
  ushort4 h, l;
  h.x = f2bf_hi(v.x, r0); h.y = f2bf_hi(v.y, r1); h.z = f2bf_hi(v.z, r2); h.w = f2bf_hi(v.w, r3);
  l.x = f2bf(r0); l.y = f2bf(r1); l.z = f2bf(r2); l.w = f2bf(r3);
  ((ushort4*)hi)[i] = h;
  ((ushort4*)lo)[i] = l;
}

__global__ void tw1_kernel(const float* __restrict__ W1, u16* __restrict__ Th, u16* __restrict__ Tl) {
  int idx = blockIdx.x*256 + threadIdx.x;      // < 512*512
  int k = idx >> 9, j = idx & 511;
  float rem; u16 hi = f2bf_hi(W1[idx], rem);
  Th[(size_t)j*512 + k] = hi;
  Tl[(size_t)j*512 + k] = f2bf(rem);
}

__global__ void tb2_kernel(const float* __restrict__ W2, u16* __restrict__ Th, u16* __restrict__ Tl) {
  int idx = blockIdx.x*256 + threadIdx.x;      // < 512*784
  int k = idx / NB2, j = idx - k*NB2;
  float v = (j < NCOL2) ? W2[(size_t)k*NCOL2 + j] : W2[(size_t)(512+k)*NCOL2 + (j - NCOL2)];
  float rem; u16 hi = f2bf_hi(v, rem);
  Th[(size_t)j*512 + k] = hi;
  Tl[(size_t)j*512 + k] = f2bf(rem);
}

// ---------------- split-bf16 MFMA GEMM ----------------
template<int EPI>
__global__ __launch_bounds__(256) void gemm_mfma(
    const u16* __restrict__ Ah, const u16* __restrict__ Al,
    const u16* __restrict__ Bh, const u16* __restrict__ Bl,
    float* __restrict__ C, int M, int Ncols,
    const int* __restrict__ cmax, const float* __restrict__ CFW, float* __restrict__ h2)
{
  __shared__ __align__(16) u16 As[2][128][40];
  __shared__ __align__(16) u16 Bs[2][128][40];
  int tid = threadIdx.x;
  int row0 = blockIdx.x * 128;
  int col0 = blockIdx.y * 128;
  int lane = tid & 63;
  int wid = tid >> 6;
  int wr = (wid >> 1) * 64;
  int wc = (wid & 1) * 64;
  int l16 = lane & 15;
  int q = lane >> 4;
  f32x4 acc[4][4];
  #pragma unroll
  for (int i = 0; i < 4; i++)
    #pragma unroll
    for (int j = 0; j < 4; j++)
      acc[i][j] = (f32x4){0.f, 0.f, 0.f, 0.f};

  int srow = tid >> 2;
  int sq = tid & 3;
  const uint4 z4 = make_uint4(0,0,0,0);

  for (int k0 = 0; k0 < 512; k0 += 32) {
    #pragma unroll
    for (int part = 0; part < 2; part++) {
      int r = part*64 + srow;
      int gm = row0 + r;
      uint4 vh = z4, vl = z4;
      if (gm < M) {
        vh = *(const uint4*)(Ah + (size_t)gm*512 + k0 + sq*8);
        vl = *(const uint4*)(Al + (size_t)gm*512 + k0 + sq*8);
      }
      *(uint4*)&As[0][r][sq*8] = vh;
      *(uint4*)&As[1][r][sq*8] = vl;
      int gn = col0 + r;
      uint4 wh = z4, wl = z4;
      if (gn < Ncols) {
        wh = *(const uint4*)(Bh + (size_t)gn*512 + k0 + sq*8);
        wl = *(const uint4*)(Bl + (size_t)gn*512 + k0 + sq*8);
      }
      *(uint4*)&Bs[0][r][sq*8] = wh;
      *(uint4*)&Bs[1][r][sq*8] = wl;
    }
    __syncthreads();
    bf16x8 ah[4], al[4], bh[4], bl[4];
    #pragma unroll
    for (int i = 0; i < 4; i++) {
      ah[i] = *(const bf16x8*)&As[0][wr + i*16 + l16][q*8];
      al[i] = *(const bf16x8*)&As[1][wr + i*16 + l16][q*8];
      bh[i] = *(const bf16x8*)&Bs[0][wc + i*16 + l16][q*8];
      bl[i] = *(const bf16x8*)&Bs[1][wc + i*16 + l16][q*8];
    }
    #pragma unroll
    for (int i = 0; i < 4; i++)
      #pragma unroll
      for (int j = 0; j < 4; j++) {
        acc[i][j] = __builtin_amdgcn_mfma_f32_16x16x32_bf16(ah[i], bh[j], acc[i][j], 0, 0, 0);
        acc[i][j] = __builtin_amdgcn_mfma_f32_16x16x32_bf16(ah[i], bl[j], acc[i][j], 0, 0, 0);
        acc[i][j] = __builtin_amdgcn_mfma_f32_16x16x32_bf16(al[i], bh[j], acc[i][j], 0, 0, 0);
      }
    __syncthreads();
  }

  if (EPI == 0) {
    #pragma unroll
    for (int i = 0; i < 4; i++) {
      #pragma unroll
      for (int r = 0; r < 4; r++) {
        int m = row0 + wr + i*16 + q*4 + r;
        if (m < M) {
          #pragma unroll
          for (int j = 0; j < 4; j++)
            C[(size_t)m*Ncols + col0 + wc + j*16 + l16] = acc[i][j][r];
        }
      }
    }
  } else {
    #pragma unroll
    for (int i = 0; i < 4; i++) {
      #pragma unroll
      for (int r = 0; r < 4; r++) {
        int m = row0 + wr + i*16 + q*4 + r;
        if (m >= M) continue;
        int c = cmax[m];
        const float* cf = CFW + (size_t)c * NB2;
        #pragma unroll
        for (int j = 0; j < 4; j++) {
          int n = col0 + wc + j*16 + l16;
          if (n >= NB2) continue;
          float v = acc[i][j][r];
          if (n < NCOL2) h2[(size_t)m*NCOL2 + n] = v + cf[NCOL2 + n];
          else           h2[(size_t)(NNODES + m)*NCOL2 + (n - NCOL2)] = v + cf[n - NCOL2];
        }
      }
    }
  }
}

// ---------------- CSR build ----------------
__global__ void hist_kernel(const int* __restrict__ ei, int* __restrict__ counts) {
  int e = blockIdx.x*256 + threadIdx.x;
  if (e < NEDGES) atomicAdd(&counts[ei[NEDGES + e]], 1);
}

__global__ __launch_bounds__(1024) void scan_kernel(const int* __restrict__ counts,
                                                    int* __restrict__ rowptr, int* __restrict__ cursor) {
  __shared__ int part[1024];
  int t = threadIdx.x;
  const int CH = 20;
  int start = t*CH;
  int end = min(start+CH, NNODES);
  int sum = 0;
  for (int i = start; i < end; i++) sum += counts[i];
  part[t] = sum;
  __syncthreads();
  for (int off = 1; off < 1024; off <<= 1) {
    int v = part[t];
    int add = (t >= off) ? part[t-off] : 0;
    __syncthreads();
    part[t] = v + add;
    __syncthreads();
  }
  int run = part[t] - sum;
  for (int i = start; i < end; i++) {
    rowptr[i] = run; cursor[i] = run;
    run += counts[i];
  }
  if (t == 1023) rowptr[NNODES] = part[1023];
}

__global__ void scatter_kernel(const int* __restrict__ ei, int* __restrict__ cursor, int* __restrict__ csr) {
  int e = blockIdx.x*256 + threadIdx.x;
  if (e < NEDGES) {
    int src = ei[e];
    int dst = ei[NEDGES + e];
    int pos = atomicAdd(&cursor[dst], 1);
    csr[pos] = src;
  }
}

// ---------------- conv1 attention logits ----------------
__global__ __launch_bounds__(256) void a1_kernel(
    const float* __restrict__ hpre, const float* __restrict__ atts, const float* __restrict__ attd,
    float* __restrict__ as1, float* __restrict__ ad1)
{
  int lane = threadIdx.x & 63;
  int i = blockIdx.x*4 + (threadIdx.x >> 6);
  const float* hp = hpre + (size_t)i*HC1 + lane*8;
  float4 h0 = *(const float4*)hp, h1 = *(const float4*)(hp+4);
  const float* ap = atts + lane*8; const float* dp = attd + lane*8;
  float4 a0 = *(const float4*)ap, a1v = *(const float4*)(ap+4);
  float4 d0 = *(const float4*)dp, d1v = *(const float4*)(dp+4);
  float ps = h0.x*a0.x + h0.y*a0.y + h0.z*a0.z + h0.w*a0.w
           + h1.x*a1v.x + h1.y*a1v.y + h1.z*a1v.z + h1.w*a1v.w;
  float pd = h0.x*d0.x + h0.y*d0.y + h0.z*d0.z + h0.w*d0.w
           + h1.x*d1v.x + h1.y*d1v.y + h1.z*d1v.z + h1.w*d1v.w;
  ps += __shfl_down(ps, 4, 8); ps += __shfl_down(ps, 2, 8); ps += __shfl_down(ps, 1, 8);
  pd += __shfl_down(pd, 4, 8); pd += __shfl_down(pd, 2, 8); pd += __shfl_down(pd, 1, 8);
  if ((lane & 7) == 0) {
    as1[i*8 + (lane >> 3)] = ps;
    ad1[i*8 + (lane >> 3)] = pd;
  }
}

// ---------------- (dst,head)-parallel softmax: writes per-edge numerators ----------------
// p[pos*8+h] = exp(e - m);  selfw = exp(eself-m)/s;  invs = 1/s
__global__ __launch_bounds__(256) void softmax1_kernel(
    const float* __restrict__ as1, const float* __restrict__ ad1,
    const int* __restrict__ rp, const int* __restrict__ csr,
    float* __restrict__ p1, float* __restrict__ selfw, float* __restrict__ invs)
{
  int gid = blockIdx.x*256 + threadIdx.x;       // < NNODES*8
  int i = gid >> 3, h = gid & 7;
  int rs = rp[i], re = rp[i+1];
  float adst = ad1[gid];
  float eself = lrelu(as1[gid] + adst);
  float m = eself;
  for (int j = rs; j < re; j++) {
    float ev = lrelu(as1[csr[j]*8 + h] + adst);
    m = fmaxf(m, ev);
  }
  float ps = __expf(eself - m);
  float s = ps;
  for (int j = rs; j < re; j++) {
    float p = __expf(lrelu(as1[csr[j]*8 + h] + adst) - m);
    p1[(size_t)j*8 + h] = p;
    s += p;
  }
  float inv = 1.f / s;
  selfw[gid] = ps * inv;
  invs[gid] = inv;
}

__global__ __launch_bounds__(256) void softmax2_kernel(
    const float* __restrict__ as2, const float* __restrict__ ad2,
    const int* __restrict__ rp, const int* __restrict__ csr,
    float* __restrict__ p2, float* __restrict__ selfw, float* __restrict__ invs)
{
  int gid = blockIdx.x*256 + threadIdx.x;       // < 2*NNODES*8
  int u = gid >> 3, h = gid & 7;
  int bn = (u < NNODES) ? u : u - NNODES;
  int off = u - bn;
  size_t eoff = (u < NNODES) ? 0 : NEDGES;
  int rs = rp[bn], re = rp[bn+1];
  float adst = ad2[gid];
  float eself = lrelu(as2[gid] + adst);
  float m = eself;
  for (int j = rs; j < re; j++) {
    float ev = lrelu(as2[(csr[j]+off)*8 + h] + adst);
    m = fmaxf(m, ev);
  }
  float ps = __expf(eself - m);
  float s = ps;
  for (int j = rs; j < re; j++) {
    float p = __expf(lrelu(as2[(csr[j]+off)*8 + h] + adst) - m);
    p2[(eoff + (size_t)j)*8 + h] = p;
    s += p;
  }
  float inv = 1.f / s;
  selfw[gid] = ps * inv;
  invs[gid] = inv;
}

// ---------------- conv1 aggregation (pure weighted gather) + ELU -> split bf16 ----------------
__global__ __launch_bounds__(256) void agg1_kernel(
    const float* __restrict__ hpre, const float* __restrict__ p1,
    const float* __restrict__ selfw, const float* __restrict__ invs,
    const int* __restrict__ rowptr, const int* __restrict__ csr, const float* __restrict__ b1,
    u16* __restrict__ hh, u16* __restrict__ hl)
{
  int lane = threadIdx.x & 63;
  int i = blockIdx.x*4 + (threadIdx.x >> 6);
  int hd = lane >> 3;
  int rs = rowptr[i];
  int deg = rowptr[i+1] - rs;
  float inv = invs[i*8 + hd];
  float asf = selfw[i*8 + hd];
  float acc[8];
  {
    const float* hp = hpre + (size_t)i*HC1 + lane*8;
    float4 v0 = *(const float4*)hp;
    float4 v1 = *(const float4*)(hp+4);
    acc[0]=asf*v0.x; acc[1]=asf*v0.y; acc[2]=asf*v0.z; acc[3]=asf*v0.w;
    acc[4]=asf*v1.x; acc[5]=asf*v1.y; acc[6]=asf*v1.z; acc[7]=asf*v1.w;
  }
  int j = 0;
  for (; j + 1 < deg; j += 2) {
    int s0 = csr[rs+j], s1 = csr[rs+j+1];
    float al0 = p1[(size_t)(rs+j)*8 + hd] * inv;
    float al1 = p1[(size_t)(rs+j+1)*8 + hd] * inv;
    const float* q0 = hpre + (size_t)s0*HC1 + lane*8;
    const float* q1 = hpre + (size_t)s1*HC1 + lane*8;
    float4 a0 = *(const float4*)q0, a1v = *(const float4*)(q0+4);
    float4 c0 = *(const float4*)q1, c1v = *(const float4*)(q1+4);
    acc[0] = fmaf(al0, a0.x, acc[0]); acc[1] = fmaf(al0, a0.y, acc[1]);
    acc[2] = fmaf(al0, a0.z, acc[2]); acc[3] = fmaf(al0, a0.w, acc[3]);
    acc[4] = fmaf(al0, a1v.x, acc[4]); acc[5] = fmaf(al0, a1v.y, acc[5]);
    acc[6] = fmaf(al0, a1v.z, acc[6]); acc[7] = fmaf(al0, a1v.w, acc[7]);
    acc[0] = fmaf(al1, c0.x, acc[0]); acc[1] = fmaf(al1, c0.y, acc[1]);
    acc[2] = fmaf(al1, c0.z, acc[2]); acc[3] = fmaf(al1, c0.w, acc[3]);
    acc[4] = fmaf(al1, c1v.x, acc[4]); acc[5] = fmaf(al1, c1v.y, acc[5]);
    acc[6] = fmaf(al1, c1v.z, acc[6]); acc[7] = fmaf(al1, c1v.w, acc[7]);
  }
  if (j < deg) {
    int s0 = csr[rs+j];
    float al0 = p1[(size_t)(rs+j)*8 + hd] * inv;
    const float* q0 = hpre + (size_t)s0*HC1 + lane*8;
    float4 a0 = *(const float4*)q0, a1v = *(const float4*)(q0+4);
    acc[0] = fmaf(al0, a0.x, acc[0]); acc[1] = fmaf(al0, a0.y, acc[1]);
    acc[2] = fmaf(al0, a0.z, acc[2]); acc[3] = fmaf(al0, a0.w, acc[3]);
    acc[4] = fmaf(al0, a1v.x, acc[4]); acc[5] = fmaf(al0, a1v.y, acc[5]);
    acc[6] = fmaf(al0, a1v.z, acc[6]); acc[7] = fmaf(al0, a1v.w, acc[7]);
  }
  u16 hh8[8], hl8[8];
  #pragma unroll
  for (int k = 0; k < 8; k++) {
    float v = acc[k] + b1[lane*8 + k];
    v = v > 0.f ? v : __expf(v) - 1.f;    // ELU
    float rem; hh8[k] = f2bf_hi(v, rem); hl8[k] = f2bf(rem);
  }
  size_t base = (size_t)i*HC1 + lane*8;
  *(ushort4*)(hh + base)     = make_ushort4(hh8[0],hh8[1],hh8[2],hh8[3]);
  *(ushort4*)(hh + base + 4) = make_ushort4(hh8[4],hh8[5],hh8[6],hh8[7]);
  *(ushort4*)(hl + base)     = make_ushort4(hl8[0],hl8[1],hl8[2],hl8[3]);
  *(ushort4*)(hl + base + 4) = make_ushort4(hl8[4],hl8[5],hl8[6],hl8[7]);
}

// ---------------- cluster stage ----------------
__global__ __launch_bounds__(256) void colsum_kernel(
    const float* __restrict__ cluster_id, const int* __restrict__ cidx, float* __restrict__ colsum)
{
  __shared__ float part[4][64];
  int tid = threadIdx.x; int q = tid >> 6, col = tid & 63;
  int start = blockIdx.x*313, end = min(start+313, NIDX);
  float acc = 0.f;
  for (int t = start + q; t < end; t += 4) {
    int node = cidx[t];
    acc += cluster_id[(size_t)node*NCLU + col];
  }
  part[q][col] = acc;
  __syncthreads();
  if (tid < 64) {
    float v = part[0][tid] + part[1][tid] + part[2][tid] + part[3][tid];
    atomicAdd(&colsum[tid], v);
  }
}

__global__ __launch_bounds__(256) void cf_kernel(
    const float* __restrict__ cluster_id, const int* __restrict__ cidx,
    const u16* __restrict__ hh, const u16* __restrict__ hl, float* __restrict__ CFraw)
{
  int tid = threadIdx.x;
  int ch = blockIdx.y*64 + (tid & 63);
  int cb = blockIdx.x*16 + (tid >> 6)*4;
  int start = blockIdx.z*400, end = start + 400;
  float a0=0.f, a1=0.f, a2=0.f, a3=0.f;
  #pragma unroll 4
  for (int t = start; t < end; t++) {
    int node = cidx[t];
    size_t idx = (size_t)node*HC1 + ch;
    float hv = bf2f(hh[idx]) + bf2f(hl[idx]);
    const float* cp = cluster_id + (size_t)node*NCLU + cb;
    a0 = fmaf(cp[0], hv, a0); a1 = fmaf(cp[1], hv, a1);
    a2 = fmaf(cp[2], hv, a2); a3 = fmaf(cp[3], hv, a3);
  }
  atomicAdd(&CFraw[(size_t)(cb+0)*HC1 + ch], a0);
  atomicAdd(&CFraw[(size_t)(cb+1)*HC1 + ch], a1);
  atomicAdd(&CFraw[(size_t)(cb+2)*HC1 + ch], a2);
  atomicAdd(&CFraw[(size_t)(cb+3)*HC1 + ch], a3);
}

__global__ __launch_bounds__(256) void argmax_kernel(const float* __restrict__ cluster_id, int* __restrict__ cmax)
{
  int lane = threadIdx.x & 63;
  int i = blockIdx.x*4 + (threadIdx.x >> 6);
  float v = cluster_id[(size_t)i*NCLU + lane];
  int idx = lane;
  #pragma unroll
  for (int off = 32; off > 0; off >>= 1) {
    float ov = __shfl_xor(v, off);
    int oi = __shfl_xor(idx, off);
    if (ov > v || (ov == v && oi < idx)) { v = ov; idx = oi; }
  }
  if (lane == 0) cmax[i] = idx;
}

__global__ __launch_bounds__(256) void cfw_kernel(
    const float* __restrict__ CFraw, const float* __restrict__ colsum,
    const float* __restrict__ W2, float* __restrict__ CFW)
{
  int o = blockIdx.x*256 + threadIdx.x;     // < 64*784
  int c = o / NB2, j = o - c*NB2;
  const float* src = (j < NCOL2) ? (W2 + j) : (W2 + (size_t)512*NCOL2 + (j - NCOL2));
  float acc = 0.f;
  for (int k = 0; k < 512; k++) acc = fmaf(CFraw[(size_t)c*512 + k], src[(size_t)k*NCOL2], acc);
  CFW[o] = acc / colsum[c];
}

// ---------------- conv2 attention logits ----------------
__global__ __launch_bounds__(256) void a2_kernel(
    const float* __restrict__ h2, const float* __restrict__ atts, const float* __restrict__ attd,
    float* __restrict__ as2, float* __restrict__ ad2)
{
  __shared__ float rows[32*NCOL2];
  __shared__ float sa[NCOL2], sd[NCOL2];
  int tid = threadIdx.x;
  size_t base = (size_t)blockIdx.x * 32 * NCOL2;
  for (int idx = tid; idx < 32*NCOL2; idx += 256) rows[idx] = h2[base + idx];
  for (int idx = tid; idx < NCOL2; idx += 256) { sa[idx] = atts[idx]; sd[idx] = attd[idx]; }
  __syncthreads();
  int r = tid >> 3, hd = tid & 7;
  const float* rp = rows + r*NCOL2 + hd*OUT2;
  const float* ap = sa + hd*OUT2;
  const float* dp = sd + hd*OUT2;
  float ps = 0.f, pd = 0.f;
  #pragma unroll
  for (int j = 0; j < OUT2; j++) { float v = rp[j]; ps = fmaf(v, ap[j], ps); pd = fmaf(v, dp[j], pd); }
  int node = blockIdx.x*32 + r;
  as2[node*8 + hd] = ps;
  ad2[node*8 + hd] = pd;
}

// ---------------- conv2 aggregation (pure weighted gather) + head-mean ----------------
__global__ __launch_bounds__(256) void agg2_kernel(
    const float* __restrict__ h2, const float* __restrict__ p2,
    const float* __restrict__ selfw, const float* __restrict__ invs,
    const int* __restrict__ rowptr, const int* __restrict__ csr, const float* __restrict__ b2,
    float* __restrict__ out)
{
  __shared__ float red[4][NCOL2];
  int lane = threadIdx.x & 63;
  int w = threadIdx.x >> 6;
  int u = blockIdx.x*4 + w;
  int bn = (u < NNODES) ? u : u - NNODES;
  int off = u - bn;
  int rs = rowptr[bn];
  int deg = rowptr[bn+1] - rs;
  size_t pbase = (size_t)rs + (off ? NEDGES : 0);
  int hk[7]; float invk[7];
  #pragma unroll
  for (int k = 0; k < 7; k++) {
    int c = lane + 64*k;
    int hx = (c < NCOL2) ? (c / OUT2) : 0;
    hk[k] = hx;
    invk[k] = (c < NCOL2) ? invs[u*8 + hx] : 0.f;
  }
  float acc[7];
  {
    const float* own = h2 + (size_t)u*NCOL2;
    #pragma unroll
    for (int k = 0; k < 7; k++) {
      int c = lane + 64*k;
      acc[k] = (c < NCOL2) ? selfw[u*8 + hk[k]] * own[c] : 0.f;
    }
  }
  int j = 0;
  for (; j + 1 < deg; j += 2) {
    int s0 = csr[rs+j] + off, s1 = csr[rs+j+1] + off;
    const float* pp0 = p2 + (pbase + j)*8;
    const float* pp1 = pp0 + 8;
    const float* r0 = h2 + (size_t)s0*NCOL2;
    const float* r1 = h2 + (size_t)s1*NCOL2;
    #pragma unroll
    for (int k = 0; k < 6; k++) {
      int c = lane + 64*k;
      acc[k] = fmaf(pp0[hk[k]]*invk[k], r0[c], acc[k]);
      acc[k] = fmaf(pp1[hk[k]]*invk[k], r1[c], acc[k]);
    }
    if (lane < 8) {
      int c = lane + 384;
      acc[6] = fmaf(pp0[hk[6]]*invk[6], r0[c], acc[6]);
      acc[6] = fmaf(pp1[hk[6]]*invk[6], r1[c], acc[6]);
    }
  }
  if (j < deg) {
    int s0 = csr[rs+j] + off;
    const float* pp0 = p2 + (pbase + j)*8;
    const float* r0 = h2 + (size_t)s0*NCOL2;
    #pragma unroll
    for (int k = 0; k < 6; k++) {
      int c = lane + 64*k;
      acc[k] = fmaf(pp0[hk[k]]*invk[k], r0[c], acc[k]);
    }
    if (lane < 8) acc[6] = fmaf(pp0[hk[6]]*invk[6], r0[lane+384], acc[6]);
  }
  #pragma unroll
  for (int k = 0; k < 7; k++) { int c = lane + 64*k; if (c < NCOL2) red[w][c] = acc[k]; }
  __syncthreads();
  if (lane < OUT2) {
    float t = 0.f;
    #pragma unroll
    for (int h = 0; h < 8; h++) t += red[w][h*OUT2 + lane];
    out[(size_t)u*OUT2 + lane] = 0.125f*t + b2[lane];
  }
}

// ---------------- launch ----------------
extern "C" void kernel_launch(void* const* d_in, const int* in_sizes, int n_in,
                              void* d_out, int out_size, void* d_ws, size_t ws_size,
                              hipStream_t stream)
{
  (void)in_sizes; (void)n_in; (void)out_size; (void)ws_size;
  const float* x     = (const float*)d_in[0];
  const int*   ei    = (const int*)d_in[1];
  const float* cid   = (const float*)d_in[2];
  const int*   cidx  = (const int*)d_in[3];
  const float* W1    = (const float*)d_in[4];
  const float* atts1 = (const float*)d_in[5];
  const float* attd1 = (const float*)d_in[6];
  const float* b1    = (const float*)d_in[7];
  const float* W2    = (const float*)d_in[8];
  const float* atts2 = (const float*)d_in[9];
  const float* attd2 = (const float*)d_in[10];
  const float* b2    = (const float*)d_in[11];
  float* out = (float*)d_out;

  char* ws = (char*)d_ws;
  size_t off = 0;
  auto alloc = [&](size_t b){ size_t r = off; off += (b + 255) & ~(size_t)255; return r; };
  size_t o_hpre = alloc((size_t)NNODES*HC1*4);
  size_t o_h2   = alloc((size_t)2*NNODES*NCOL2*4);
  size_t o_xh   = alloc((size_t)NNODES*FIN*2);
  size_t o_xl   = alloc((size_t)NNODES*FIN*2);
  size_t o_hh   = alloc((size_t)NNODES*HC1*2);
  size_t o_hl   = alloc((size_t)NNODES*HC1*2);
  size_t o_w1h  = alloc((size_t)512*512*2);
  size_t o_w1l  = alloc((size_t)512*512*2);
  size_t o_b2h  = alloc((size_t)NB2*512*2);
  size_t o_b2l  = alloc((size_t)NB2*512*2);
  size_t o_CFW  = alloc((size_t)NCLU*NB2*4);
  size_t o_as1  = alloc((size_t)NNODES*8*4);
  size_t o_ad1  = alloc((size_t)NNODES*8*4);
  size_t o_as2  = alloc((size_t)2*NNODES*8*4);
  size_t o_ad2  = alloc((size_t)2*NNODES*8*4);
  size_t o_rp   = alloc((size_t)(NNODES+1)*4);
  size_t o_cur  = alloc((size_t)NNODES*4);
  size_t o_csr  = alloc((size_t)NEDGES*4);
  size_t o_cmax = alloc((size_t)NNODES*4);
  size_t o_cnt  = alloc((size_t)NNODES*4);
  size_t o_csum = alloc(256 + (size_t)NCLU*HC1*4);

  float* hpre  = (float*)(ws + o_hpre);
  float* h2    = (float*)(ws + o_h2);
  u16*   xh    = (u16*)(ws + o_xh);
  u16*   xl    = (u16*)(ws + o_xl);
  u16*   hh    = (u16*)(ws + o_hh);
  u16*   hl    = (u16*)(ws + o_hl);
  u16*   w1h   = (u16*)(ws + o_w1h);
  u16*   w1l   = (u16*)(ws + o_w1l);
  u16*   b2h   = (u16*)(ws + o_b2h);
  u16*   b2l   = (u16*)(ws + o_b2l);
  float* CFW   = (float*)(ws + o_CFW);
  float* as1   = (float*)(ws + o_as1);
  float* ad1   = (float*)(ws + o_ad1);
  float* as2   = (float*)(ws + o_as2);
  float* ad2   = (float*)(ws + o_ad2);
  int*   rp    = (int*)(ws + o_rp);
  int*   cur   = (int*)(ws + o_cur);
  int*   csr   = (int*)(ws + o_csr);
  int*   cmax  = (int*)(ws + o_cmax);
  int*   cnt   = (int*)(ws + o_cnt);
  float* colsum= (float*)(ws + o_csum);
  float* CFraw = (float*)(ws + o_csum + 256);

  // softmax buffers overlay the xh/xl region (dead after gemm1; 34.56MB <= 40.96MB)
  char* ov = ws + o_xh;
  float* p1  = (float*)ov;                                   // E*8*4      = 10,240,000
  float* p2  = (float*)(ov + 10240000);                      // 2E*8*4     = 20,480,000
  float* sw1 = (float*)(ov + 30720000);                      // N*8*4
  float* iv1 = sw1 + NNODES*8;
  float* sw2 = iv1 + NNODES*8;                               // 2N*8*4
  float* iv2 = sw2 + 2*NNODES*8;

  hipMemsetAsync(ws + o_cnt, 0, (size_t)NNODES*4, stream);
  hipMemsetAsync(ws + o_csum, 0, 256 + (size_t)NCLU*HC1*4, stream);

  // input splits
  split4_kernel<<<NNODES*FIN/4/256, 256, 0, stream>>>(x, xh, xl);
  tw1_kernel<<<1024, 256, 0, stream>>>(W1, w1h, w1l);
  // CSR (shared by both convs)
  hist_kernel<<<1250, 256, 0, stream>>>(ei, cnt);
  scan_kernel<<<1, 1024, 0, stream>>>(cnt, rp, cur);
  scatter_kernel<<<1250, 256, 0, stream>>>(ei, cur, csr);
  // conv1 linear (MFMA split-bf16)
  gemm_mfma<0><<<dim3(157,4), 256, 0, stream>>>(xh, xl, w1h, w1l, hpre, NNODES, 512, nullptr, nullptr, nullptr);
  // conv1 attention (logits -> softmax numerators -> gather)
  a1_kernel<<<5000, 256, 0, stream>>>(hpre, atts1, attd1, as1, ad1);
  softmax1_kernel<<<625, 256, 0, stream>>>(as1, ad1, rp, csr, p1, sw1, iv1);
  agg1_kernel<<<5000, 256, 0, stream>>>(hpre, p1, sw1, iv1, rp, csr, b1, hh, hl);
  // cluster features
  tb2_kernel<<<1568, 256, 0, stream>>>(W2, b2h, b2l);
  colsum_kernel<<<32, 256, 0, stream>>>(cid, cidx, colsum);
  cf_kernel<<<dim3(4,8,25), 256, 0, stream>>>(cid, cidx, hh, hl, CFraw);
  argmax_kernel<<<5000, 256, 0, stream>>>(cid, cmax);
  cfw_kernel<<<196, 256, 0, stream>>>(CFraw, colsum, W2, CFW);
  // conv2 linear (MFMA split-bf16) with fused x1-add + scatter into h2 [2N,392]
  gemm_mfma<1><<<dim3(157,7), 256, 0, stream>>>(hh, hl, b2h, b2l, nullptr, NNODES, NB2, cmax, CFW, h2);
  // conv2 attention
  a2_kernel<<<1250, 256, 0, stream>>>(h2, atts2, attd2, as2, ad2);
  softmax2_kernel<<<1250, 256, 0, stream>>>(as2, ad2, rp, csr, p2, sw2, iv2);
  agg2_kernel<<<10000, 256, 0, stream>>>(h2, p2, sw2, iv2, rp, csr, b2, out);
}

// Round 4
// 723.412 us; speedup vs baseline: 1.5665x; 1.1517x over previous
//
#include <hip/hip_runtime.h>

#define NNODES 20000
#define NEDGES 320000
#define FIN    512
#define HC1    512      // H1*HID
#define NHEAD  8
#define OUT2   49
#define NCOL2  392      // NHEAD*OUT2
#define NB2    784      // 2*NCOL2
#define NCLU   64
#define NIDX   10000
#define NEG    0.2f

typedef unsigned short u16;
typedef short bf16x8 __attribute__((ext_vector_type(8)));
typedef float f32x4 __attribute__((ext_vector_type(4)));

static __device__ __forceinline__ float lrelu(float v){ return v > 0.f ? v : NEG*v; }

// exact split (truncation): f = hi + rem, hi has 8-bit mantissa
static __device__ __forceinline__ u16 f2bf_hi(float f, float& rem) {
  union { float f; unsigned u; } c; c.f = f;
  unsigned hb = c.u & 0xFFFF0000u;
  union { unsigned u; float f; } d; d.u = hb;
  rem = f - d.f;
  return (u16)(hb >> 16);
}
static __device__ __forceinline__ u16 f2bf(float f) {   // truncate
  union { float f; unsigned u; } c; c.f = f;
  return (u16)(c.u >> 16);
}
static __device__ __forceinline__ u16 f2bf_rn(float f) { // round-nearest-even
  union { float f; unsigned u; } c; c.f = f;
  unsigned r = c.u + 0x7FFFu + ((c.u >> 16) & 1u);
  return (u16)(r >> 16);
}
static __device__ __forceinline__ float bf2f(u16 u) {
  union { unsigned u; float f; } c; c.u = ((unsigned)u) << 16;
  return c.f;
}
static __device__ __forceinline__ void load8bf(const u16* p, float* o) {
  ushort4 a = *(const ushort4*)p;
  ushort4 b = *(const ushort4*)(p + 4);
  o[0]=bf2f(a.x); o[1]=bf2f(a.y); o[2]=bf2f(a.z); o[3]=bf2f(a.w);
  o[4]=bf2f(b.x); o[5]=bf2f(b.y); o[6]=bf2f(b.z); o[7]=bf2f(b.w);
}

// ---------------- weight split kernels ----------------
__global__ void tw1_kernel(const float* __restrict__ W1, u16* __restrict__ Th, u16* __restrict__ Tl) {
  int idx = blockIdx.x*256 + threadIdx.x;      // < 512*512
  int k = idx >> 9, j = idx & 511;
  float rem; u16 hi = f2bf_hi(W1[idx], rem);
  Th[(size_t)j*512 + k] = hi;
  Tl[(size_t)j*512 + k] = f2bf(rem);
}

__global__ void tb2_kernel(const float* __restrict__ W2, u16* __restrict__ Th, u16* __restrict__ Tl) {
  int idx = blockIdx.x*256 + threadIdx.x;      // < 512*784
  int k = idx / NB2, j = idx - k*NB2;
  float v = (j < NCOL2) ? W2[(size_t)k*NCOL2 + j] : W2[(size_t)(512+k)*NCOL2 + (j - NCOL2)];
  float rem; u16 hi = f2bf_hi(v, rem);
  Th[(size_t)j*512 + k] = hi;
  Tl[(size_t)j*512 + k] = f2bf(rem);
}

// ---------------- split-bf16 MFMA GEMM, fp32 A split in staging ----------------
// C ~= Ah Bh + Ah Bl + Al Bh ; EPI=0: write bf16 C [M,Ncols]; EPI=1: bf16 h2 scatter with CFW add
template<int EPI>
__global__ __launch_bounds__(256) void gemm_mfma(
    const float* __restrict__ A,
    const u16* __restrict__ Bh, const u16* __restrict__ Bl,
    u16* __restrict__ Cbf, int M, int Ncols,
    const int* __restrict__ cmax, const float* __restrict__ CFW, u16* __restrict__ h2)
{
  __shared__ __align__(16) u16 As[2][128][40];
  __shared__ __align__(16) u16 Bs[2][128][40];
  int tid = threadIdx.x;
  int row0 = blockIdx.x * 128;
  int col0 = blockIdx.y * 128;
  int lane = tid & 63;
  int wid = tid >> 6;
  int wr = (wid >> 1) * 64;
  int wc = (wid & 1) * 64;
  int l16 = lane & 15;
  int q = lane >> 4;
  f32x4 acc[4][4];
  #pragma unroll
  for (int i = 0; i < 4; i++)
    #pragma unroll
    for (int j = 0; j < 4; j++)
      acc[i][j] = (f32x4){0.f, 0.f, 0.f, 0.f};

  int srow = tid >> 2;
  int sq = tid & 3;
  const uint4 z4 = make_uint4(0,0,0,0);

  for (int k0 = 0; k0 < 512; k0 += 32) {
    #pragma unroll
    for (int part = 0; part < 2; part++) {
      int r = part*64 + srow;
      int gm = row0 + r;
      float4 v0 = make_float4(0.f,0.f,0.f,0.f), v1 = v0;
      if (gm < M) {
        v0 = *(const float4*)(A + (size_t)gm*512 + k0 + sq*8);
        v1 = *(const float4*)(A + (size_t)gm*512 + k0 + sq*8 + 4);
      }
      float rem;
      ushort4 h0, l0, h1, l1;
      h0.x = f2bf_hi(v0.x, rem); l0.x = f2bf(rem);
      h0.y = f2bf_hi(v0.y, rem); l0.y = f2bf(rem);
      h0.z = f2bf_hi(v0.z, rem); l0.z = f2bf(rem);
      h0.w = f2bf_hi(v0.w, rem); l0.w = f2bf(rem);
      h1.x = f2bf_hi(v1.x, rem); l1.x = f2bf(rem);
      h1.y = f2bf_hi(v1.y, rem); l1.y = f2bf(rem);
      h1.z = f2bf_hi(v1.z, rem); l1.z = f2bf(rem);
      h1.w = f2bf_hi(v1.w, rem); l1.w = f2bf(rem);
      *(ushort4*)&As[0][r][sq*8]     = h0;
      *(ushort4*)&As[0][r][sq*8 + 4] = h1;
      *(ushort4*)&As[1][r][sq*8]     = l0;
      *(ushort4*)&As[1][r][sq*8 + 4] = l1;
      int gn = col0 + r;
      uint4 wh = z4, wl = z4;
      if (gn < Ncols) {
        wh = *(const uint4*)(Bh + (size_t)gn*512 + k0 + sq*8);
        wl = *(const uint4*)(Bl + (size_t)gn*512 + k0 + sq*8);
      }
      *(uint4*)&Bs[0][r][sq*8] = wh;
      *(uint4*)&Bs[1][r][sq*8] = wl;
    }
    __syncthreads();
    bf16x8 ah[4], al[4], bh[4], bl[4];
    #pragma unroll
    for (int i = 0; i < 4; i++) {
      ah[i] = *(const bf16x8*)&As[0][wr + i*16 + l16][q*8];
      al[i] = *(const bf16x8*)&As[1][wr + i*16 + l16][q*8];
      bh[i] = *(const bf16x8*)&Bs[0][wc + i*16 + l16][q*8];
      bl[i] = *(const bf16x8*)&Bs[1][wc + i*16 + l16][q*8];
    }
    #pragma unroll
    for (int i = 0; i < 4; i++)
      #pragma unroll
      for (int j = 0; j < 4; j++) {
        acc[i][j] = __builtin_amdgcn_mfma_f32_16x16x32_bf16(ah[i], bh[j], acc[i][j], 0, 0, 0);
        acc[i][j] = __builtin_amdgcn_mfma_f32_16x16x32_bf16(ah[i], bl[j], acc[i][j], 0, 0, 0);
        acc[i][j] = __builtin_amdgcn_mfma_f32_16x16x32_bf16(al[i], bh[j], acc[i][j], 0, 0, 0);
      }
    __syncthreads();
  }

  if (EPI == 0) {
    #pragma unroll
    for (int i = 0; i < 4; i++) {
      #pragma unroll
      for (int r = 0; r < 4; r++) {
        int m = row0 + wr + i*16 + q*4 + r;
        if (m < M) {
          #pragma unroll
          for (int j = 0; j < 4; j++)
            Cbf[(size_t)m*Ncols + col0 + wc + j*16 + l16] = f2bf_rn(acc[i][j][r]);
        }
      }
    }
  } else {
    #pragma unroll
    for (int i = 0; i < 4; i++) {
      #pragma unroll
      for (int r = 0; r < 4; r++) {
        int m = row0 + wr + i*16 + q*4 + r;
        if (m >= M) continue;
        int c = cmax[m];
        const float* cf = CFW + (size_t)c * NB2;
        #pragma unroll
        for (int j = 0; j < 4; j++) {
          int n = col0 + wc + j*16 + l16;
          if (n >= NB2) continue;
          float v = acc[i][j][r];
          if (n < NCOL2) h2[(size_t)m*NCOL2 + n] = f2bf_rn(v + cf[NCOL2 + n]);
          else           h2[(size_t)(NNODES + m)*NCOL2 + (n - NCOL2)] = f2bf_rn(v + cf[n - NCOL2]);
        }
      }
    }
  }
}

// ---------------- CSR build ----------------
__global__ void hist_kernel(const int* __restrict__ ei, int* __restrict__ counts) {
  int e = blockIdx.x*256 + threadIdx.x;
  if (e < NEDGES) atomicAdd(&counts[ei[NEDGES + e]], 1);
}

__global__ __launch_bounds__(1024) void scan_kernel(const int* __restrict__ counts,
                                                    int* __restrict__ rowptr, int* __restrict__ cursor) {
  __shared__ int part[1024];
  int t = threadIdx.x;
  const int CH = 20;
  int start = t*CH;
  int end = min(start+CH, NNODES);
  int sum = 0;
  for (int i = start; i < end; i++) sum += counts[i];
  part[t] = sum;
  __syncthreads();
  for (int off = 1; off < 1024; off <<= 1) {
    int v = part[t];
    int add = (t >= off) ? part[t-off] : 0;
    __syncthreads();
    part[t] = v + add;
    __syncthreads();
  }
  int run = part[t] - sum;
  for (int i = start; i < end; i++) {
    rowptr[i] = run; cursor[i] = run;
    run += counts[i];
  }
  if (t == 1023) rowptr[NNODES] = part[1023];
}

__global__ void scatter_kernel(const int* __restrict__ ei, int* __restrict__ cursor, int* __restrict__ csr) {
  int e = blockIdx.x*256 + threadIdx.x;
  if (e < NEDGES) {
    int src = ei[e];
    int dst = ei[NEDGES + e];
    int pos = atomicAdd(&cursor[dst], 1);
    csr[pos] = src;
  }
}

// ---------------- conv1 attention logits (bf16 hpre) ----------------
__global__ __launch_bounds__(256) void a1_kernel(
    const u16* __restrict__ hpre, const float* __restrict__ atts, const float* __restrict__ attd,
    float* __restrict__ as1, float* __restrict__ ad1)
{
  int lane = threadIdx.x & 63;
  int i = blockIdx.x*4 + (threadIdx.x >> 6);
  float hv[8];
  load8bf(hpre + (size_t)i*HC1 + lane*8, hv);
  const float* ap = atts + lane*8; const float* dp = attd + lane*8;
  float ps = 0.f, pd = 0.f;
  #pragma unroll
  for (int k = 0; k < 8; k++) { ps = fmaf(hv[k], ap[k], ps); pd = fmaf(hv[k], dp[k], pd); }
  ps += __shfl_down(ps, 4, 8); ps += __shfl_down(ps, 2, 8); ps += __shfl_down(ps, 1, 8);
  pd += __shfl_down(pd, 4, 8); pd += __shfl_down(pd, 2, 8); pd += __shfl_down(pd, 1, 8);
  if ((lane & 7) == 0) {
    as1[i*8 + (lane >> 3)] = ps;
    ad1[i*8 + (lane >> 3)] = pd;
  }
}

// ---------------- single-pass (dst,head)-parallel softmax ----------------
__global__ __launch_bounds__(256) void softmax1_kernel(
    const float* __restrict__ as1, const float* __restrict__ ad1,
    const int* __restrict__ rp, const int* __restrict__ csr,
    float* __restrict__ p1, float* __restrict__ selfw, float* __restrict__ invs)
{
  int gid = blockIdx.x*256 + threadIdx.x;       // < NNODES*8
  int i = gid >> 3, h = gid & 7;
  int rs = rp[i], re = rp[i+1];
  float adst = ad1[gid];
  float ps = __expf(lrelu(as1[gid] + adst));
  float s = ps;
  for (int j = rs; j < re; j++) {
    float p = __expf(lrelu(as1[csr[j]*8 + h] + adst));
    p1[(size_t)j*8 + h] = p;
    s += p;
  }
  float inv = 1.f / s;
  selfw[gid] = ps * inv;
  invs[gid] = inv;
}

__global__ __launch_bounds__(256) void softmax2_kernel(
    const float* __restrict__ as2, const float* __restrict__ ad2,
    const int* __restrict__ rp, const int* __restrict__ csr,
    float* __restrict__ p2, float* __restrict__ selfw, float* __restrict__ invs)
{
  int gid = blockIdx.x*256 + threadIdx.x;       // < 2*NNODES*8
  int u = gid >> 3, h = gid & 7;
  int bn = (u < NNODES) ? u : u - NNODES;
  int off = u - bn;
  size_t eoff = (u < NNODES) ? 0 : NEDGES;
  int rs = rp[bn], re = rp[bn+1];
  float adst = ad2[gid];
  float ps = __expf(lrelu(as2[gid] + adst));
  float s = ps;
  for (int j = rs; j < re; j++) {
    float p = __expf(lrelu(as2[(csr[j]+off)*8 + h] + adst));
    p2[(eoff + (size_t)j)*8 + h] = p;
    s += p;
  }
  float inv = 1.f / s;
  selfw[gid] = ps * inv;
  invs[gid] = inv;
}

// ---------------- conv1 aggregation (bf16 gather) + ELU -> fp32 h ----------------
__global__ __launch_bounds__(256) void agg1_kernel(
    const u16* __restrict__ hpre, const float* __restrict__ p1,
    const float* __restrict__ selfw, const float* __restrict__ invs,
    const int* __restrict__ rowptr, const int* __restrict__ csr, const float* __restrict__ b1,
    float* __restrict__ hout)
{
  int lane = threadIdx.x & 63;
  int i = blockIdx.x*4 + (threadIdx.x >> 6);
  int hd = lane >> 3;
  int rs = rowptr[i];
  int deg = rowptr[i+1] - rs;
  float inv = invs[i*8 + hd];
  float asf = selfw[i*8 + hd];
  float acc[8];
  {
    float v[8];
    load8bf(hpre + (size_t)i*HC1 + lane*8, v);
    #pragma unroll
    for (int k = 0; k < 8; k++) acc[k] = asf * v[k];
  }
  int j = 0;
  for (; j + 1 < deg; j += 2) {
    int s0 = csr[rs+j], s1 = csr[rs+j+1];
    float al0 = p1[(size_t)(rs+j)*8 + hd] * inv;
    float al1 = p1[(size_t)(rs+j+1)*8 + hd] * inv;
    float v0[8], v1[8];
    load8bf(hpre + (size_t)s0*HC1 + lane*8, v0);
    load8bf(hpre + (size_t)s1*HC1 + lane*8, v1);
    #pragma unroll
    for (int k = 0; k < 8; k++) acc[k] = fmaf(al0, v0[k], acc[k]);
    #pragma unroll
    for (int k = 0; k < 8; k++) acc[k] = fmaf(al1, v1[k], acc[k]);
  }
  if (j < deg) {
    int s0 = csr[rs+j];
    float al0 = p1[(size_t)(rs+j)*8 + hd] * inv;
    float v0[8];
    load8bf(hpre + (size_t)s0*HC1 + lane*8, v0);
    #pragma unroll
    for (int k = 0; k < 8; k++) acc[k] = fmaf(al0, v0[k], acc[k]);
  }
  float o[8];
  #pragma unroll
  for (int k = 0; k < 8; k++) {
    float v = acc[k] + b1[lane*8 + k];
    o[k] = v > 0.f ? v : __expf(v) - 1.f;   // ELU
  }
  float* ho = hout + (size_t)i*HC1 + lane*8;
  *(float4*)ho     = make_float4(o[0],o[1],o[2],o[3]);
  *(float4*)(ho+4) = make_float4(o[4],o[5],o[6],o[7]);
}

// ---------------- cluster stage ----------------
__global__ __launch_bounds__(256) void colsum_kernel(
    const float* __restrict__ cluster_id, const int* __restrict__ cidx, float* __restrict__ colsum)
{
  __shared__ float part[4][64];
  int tid = threadIdx.x; int q = tid >> 6, col = tid & 63;
  int start = blockIdx.x*313, end = min(start+313, NIDX);
  float acc = 0.f;
  for (int t = start + q; t < end; t += 4) {
    int node = cidx[t];
    acc += cluster_id[(size_t)node*NCLU + col];
  }
  part[q][col] = acc;
  __syncthreads();
  if (tid < 64) {
    float v = part[0][tid] + part[1][tid] + part[2][tid] + part[3][tid];
    atomicAdd(&colsum[tid], v);
  }
}

__global__ __launch_bounds__(256) void cf_kernel(
    const float* __restrict__ cluster_id, const int* __restrict__ cidx,
    const float* __restrict__ h, float* __restrict__ CFraw)
{
  int tid = threadIdx.x;
  int ch = blockIdx.y*64 + (tid & 63);
  int cb = blockIdx.x*16 + (tid >> 6)*4;
  int start = blockIdx.z*400, end = start + 400;
  float a0=0.f, a1=0.f, a2=0.f, a3=0.f;
  #pragma unroll 4
  for (int t = start; t < end; t++) {
    int node = cidx[t];
    float hv = h[(size_t)node*HC1 + ch];
    const float* cp = cluster_id + (size_t)node*NCLU + cb;
    a0 = fmaf(cp[0], hv, a0); a1 = fmaf(cp[1], hv, a1);
    a2 = fmaf(cp[2], hv, a2); a3 = fmaf(cp[3], hv, a3);
  }
  atomicAdd(&CFraw[(size_t)(cb+0)*HC1 + ch], a0);
  atomicAdd(&CFraw[(size_t)(cb+1)*HC1 + ch], a1);
  atomicAdd(&CFraw[(size_t)(cb+2)*HC1 + ch], a2);
  atomicAdd(&CFraw[(size_t)(cb+3)*HC1 + ch], a3);
}

__global__ __launch_bounds__(256) void argmax_kernel(const float* __restrict__ cluster_id, int* __restrict__ cmax)
{
  int lane = threadIdx.x & 63;
  int i = blockIdx.x*4 + (threadIdx.x >> 6);
  float v = cluster_id[(size_t)i*NCLU + lane];
  int idx = lane;
  #pragma unroll
  for (int off = 32; off > 0; off >>= 1) {
    float ov = __shfl_xor(v, off);
    int oi = __shfl_xor(idx, off);
    if (ov > v || (ov == v && oi < idx)) { v = ov; idx = oi; }
  }
  if (lane == 0) cmax[i] = idx;
}

__global__ __launch_bounds__(256) void cfw_kernel(
    const float* __restrict__ CFraw, const float* __restrict__ colsum,
    const float* __restrict__ W2, float* __restrict__ CFW)
{
  int o = blockIdx.x*256 + threadIdx.x;     // < 64*784
  int c = o / NB2, j = o - c*NB2;
  const float* src = (j < NCOL2) ? (W2 + j) : (W2 + (size_t)512*NCOL2 + (j - NCOL2));
  float acc = 0.f;
  for (int k = 0; k < 512; k++) acc = fmaf(CFraw[(size_t)c*512 + k], src[(size_t)k*NCOL2], acc);
  CFW[o] = acc / colsum[c];
}

// ---------------- conv2 attention logits (bf16 h2) ----------------
__global__ __launch_bounds__(256) void a2_kernel(
    const u16* __restrict__ h2, const float* __restrict__ atts, const float* __restrict__ attd,
    float* __restrict__ as2, float* __restrict__ ad2)
{
  __shared__ float rows[32*NCOL2];
  __shared__ float sa[NCOL2], sd[NCOL2];
  int tid = threadIdx.x;
  size_t base = (size_t)blockIdx.x * 32 * NCOL2;
  for (int idx = tid; idx < 32*NCOL2; idx += 256) rows[idx] = bf2f(h2[base + idx]);
  for (int idx = tid; idx < NCOL2; idx += 256) { sa[idx] = atts[idx]; sd[idx] = attd[idx]; }
  __syncthreads();
  int r = tid >> 3, hd = tid & 7;
  const float* rp = rows + r*NCOL2 + hd*OUT2;
  const float* ap = sa + hd*OUT2;
  const float* dp = sd + hd*OUT2;
  float ps = 0.f, pd = 0.f;
  #pragma unroll
  for (int j = 0; j < OUT2; j++) { float v = rp[j]; ps = fmaf(v, ap[j], ps); pd = fmaf(v, dp[j], pd); }
  int node = blockIdx.x*32 + r;
  as2[node*8 + hd] = ps;
  ad2[node*8 + hd] = pd;
}

// ---------------- conv2 aggregation (bf16 gather) + head-mean ----------------
__global__ __launch_bounds__(256) void agg2_kernel(
    const u16* __restrict__ h2, const float* __restrict__ p2,
    const float* __restrict__ selfw, const float* __restrict__ invs,
    const int* __restrict__ rowptr, const int* __restrict__ csr, const float* __restrict__ b2,
    float* __restrict__ out)
{
  __shared__ float red[4][NCOL2];
  int lane = threadIdx.x & 63;
  int w = threadIdx.x >> 6;
  int u = blockIdx.x*4 + w;
  int bn = (u < NNODES) ? u : u - NNODES;
  int off = u - bn;
  int rs = rowptr[bn];
  int deg = rowptr[bn+1] - rs;
  size_t pbase = (size_t)rs + (off ? NEDGES : 0);
  int hk[7]; float invk[7];
  #pragma unroll
  for (int k = 0; k < 7; k++) {
    int c = lane + 64*k;
    int hx = (c < NCOL2) ? (c / OUT2) : 0;
    hk[k] = hx;
    invk[k] = (c < NCOL2) ? invs[u*8 + hx] : 0.f;
  }
  float acc[7];
  {
    const u16* own = h2 + (size_t)u*NCOL2;
    #pragma unroll
    for (int k = 0; k < 7; k++) {
      int c = lane + 64*k;
      acc[k] = (c < NCOL2) ? selfw[u*8 + hk[k]] * bf2f(own[c]) : 0.f;
    }
  }
  int j = 0;
  for (; j + 1 < deg; j += 2) {
    int s0 = csr[rs+j] + off, s1 = csr[rs+j+1] + off;
    const float* pp0 = p2 + (pbase + j)*8;
    const float* pp1 = pp0 + 8;
    const u16* r0 = h2 + (size_t)s0*NCOL2;
    const u16* r1 = h2 + (size_t)s1*NCOL2;
    #pragma unroll
    for (int k = 0; k < 6; k++) {
      int c = lane + 64*k;
      acc[k] = fmaf(pp0[hk[k]]*invk[k], bf2f(r0[c]), acc[k]);
      acc[k] = fmaf(pp1[hk[k]]*invk[k], bf2f(r1[c]), acc[k]);
    }
    if (lane < 8) {
      int c = lane + 384;
      acc[6] = fmaf(pp0[hk[6]]*invk[6], bf2f(r0[c]), acc[6]);
      acc[6] = fmaf(pp1[hk[6]]*invk[6], bf2f(r1[c]), acc[6]);
    }
  }
  if (j < deg) {
    int s0 = csr[rs+j] + off;
    const float* pp0 = p2 + (pbase + j)*8;
    const u16* r0 = h2 + (size_t)s0*NCOL2;
    #pragma unroll
    for (int k = 0; k < 6; k++) {
      int c = lane + 64*k;
      acc[k] = fmaf(pp0[hk[k]]*invk[k], bf2f(r0[c]), acc[k]);
    }
    if (lane < 8) acc[6] = fmaf(pp0[hk[6]]*invk[6], bf2f(r0[lane+384]), acc[6]);
  }
  #pragma unroll
  for (int k = 0; k < 7; k++) { int c = lane + 64*k; if (c < NCOL2) red[w][c] = acc[k]; }
  __syncthreads();
  if (lane < OUT2) {
    float t = 0.f;
    #pragma unroll
    for (int h = 0; h < 8; h++) t += red[w][h*OUT2 + lane];
    out[(size_t)u*OUT2 + lane] = 0.125f*t + b2[lane];
  }
}

// ---------------- launch ----------------
extern "C" void kernel_launch(void* const* d_in, const int* in_sizes, int n_in,
                              void* d_out, int out_size, void* d_ws, size_t ws_size,
                              hipStream_t stream)
{
  (void)in_sizes; (void)n_in; (void)out_size; (void)ws_size;
  const float* x     = (const float*)d_in[0];
  const int*   ei    = (const int*)d_in[1];
  const float* cid   = (const float*)d_in[2];
  const int*   cidx  = (const int*)d_in[3];
  const float* W1    = (const float*)d_in[4];
  const float* atts1 = (const float*)d_in[5];
  const float* attd1 = (const float*)d_in[6];
  const float* b1    = (const float*)d_in[7];
  const float* W2    = (const float*)d_in[8];
  const float* atts2 = (const float*)d_in[9];
  const float* attd2 = (const float*)d_in[10];
  const float* b2    = (const float*)d_in[11];
  float* out = (float*)d_out;

  char* ws = (char*)d_ws;
  size_t off = 0;
  auto alloc = [&](size_t b){ size_t r = off; off += (b + 255) & ~(size_t)255; return r; };
  size_t o_hpre = alloc((size_t)NNODES*HC1*2);        // bf16
  size_t o_h    = alloc((size_t)NNODES*HC1*4);        // fp32
  size_t o_h2   = alloc((size_t)2*NNODES*NCOL2*2);    // bf16
  size_t o_w1h  = alloc((size_t)512*512*2);
  size_t o_w1l  = alloc((size_t)512*512*2);
  size_t o_b2h  = alloc((size_t)NB2*512*2);
  size_t o_b2l  = alloc((size_t)NB2*512*2);
  size_t o_CFW  = alloc((size_t)NCLU*NB2*4);
  size_t o_as1  = alloc((size_t)NNODES*8*4);
  size_t o_ad1  = alloc((size_t)NNODES*8*4);
  size_t o_as2  = alloc((size_t)2*NNODES*8*4);
  size_t o_ad2  = alloc((size_t)2*NNODES*8*4);
  size_t o_p1   = alloc((size_t)NEDGES*8*4);
  size_t o_p2   = alloc((size_t)2*NEDGES*8*4);
  size_t o_sw1  = alloc((size_t)NNODES*8*4);
  size_t o_iv1  = alloc((size_t)NNODES*8*4);
  size_t o_sw2  = alloc((size_t)2*NNODES*8*4);
  size_t o_iv2  = alloc((size_t)2*NNODES*8*4);
  size_t o_rp   = alloc((size_t)(NNODES+1)*4);
  size_t o_cur  = alloc((size_t)NNODES*4);
  size_t o_csr  = alloc((size_t)NEDGES*4);
  size_t o_cmax = alloc((size_t)NNODES*4);
  size_t o_cnt  = alloc((size_t)NNODES*4);
  size_t o_csum = alloc(256 + (size_t)NCLU*HC1*4);

  u16*   hpre  = (u16*)(ws + o_hpre);
  float* h     = (float*)(ws + o_h);
  u16*   h2    = (u16*)(ws + o_h2);
  u16*   w1h   = (u16*)(ws + o_w1h);
  u16*   w1l   = (u16*)(ws + o_w1l);
  u16*   b2h   = (u16*)(ws + o_b2h);
  u16*   b2l   = (u16*)(ws + o_b2l);
  float* CFW   = (float*)(ws + o_CFW);
  float* as1   = (float*)(ws + o_as1);
  float* ad1   = (float*)(ws + o_ad1);
  float* as2   = (float*)(ws + o_as2);
  float* ad2   = (float*)(ws + o_ad2);
  float* p1    = (float*)(ws + o_p1);
  float* p2    = (float*)(ws + o_p2);
  float* sw1   = (float*)(ws + o_sw1);
  float* iv1   = (float*)(ws + o_iv1);
  float* sw2   = (float*)(ws + o_sw2);
  float* iv2   = (float*)(ws + o_iv2);
  int*   rp    = (int*)(ws + o_rp);
  int*   cur   = (int*)(ws + o_cur);
  int*   csr   = (int*)(ws + o_csr);
  int*   cmax  = (int*)(ws + o_cmax);
  int*   cnt   = (int*)(ws + o_cnt);
  float* colsum= (float*)(ws + o_csum);
  float* CFraw = (float*)(ws + o_csum + 256);

  hipMemsetAsync(ws + o_cnt, 0, (size_t)NNODES*4, stream);
  hipMemsetAsync(ws + o_csum, 0, 256 + (size_t)NCLU*HC1*4, stream);

  // weight splits
  tw1_kernel<<<1024, 256, 0, stream>>>(W1, w1h, w1l);
  tb2_kernel<<<1568, 256, 0, stream>>>(W2, b2h, b2l);
  // CSR (shared by both convs)
  hist_kernel<<<1250, 256, 0, stream>>>(ei, cnt);
  scan_kernel<<<1, 1024, 0, stream>>>(cnt, rp, cur);
  scatter_kernel<<<1250, 256, 0, stream>>>(ei, cur, csr);
  // conv1 linear (fp32 A split in staging) -> bf16 hpre
  gemm_mfma<0><<<dim3(157,4), 256, 0, stream>>>(x, w1h, w1l, hpre, NNODES, 512, nullptr, nullptr, nullptr);
  // conv1 attention
  a1_kernel<<<5000, 256, 0, stream>>>(hpre, atts1, attd1, as1, ad1);
  softmax1_kernel<<<625, 256, 0, stream>>>(as1, ad1, rp, csr, p1, sw1, iv1);
  agg1_kernel<<<5000, 256, 0, stream>>>(hpre, p1, sw1, iv1, rp, csr, b1, h);
  // cluster features
  colsum_kernel<<<32, 256, 0, stream>>>(cid, cidx, colsum);
  cf_kernel<<<dim3(4,8,25), 256, 0, stream>>>(cid, cidx, h, CFraw);
  argmax_kernel<<<5000, 256, 0, stream>>>(cid, cmax);
  cfw_kernel<<<196, 256, 0, stream>>>(CFraw, colsum, W2, CFW);
  // conv2 linear -> bf16 h2 [2N,392] with fused x1-add
  gemm_mfma<1><<<dim3(157,7), 256, 0, stream>>>(h, b2h, b2l, nullptr, NNODES, NB2, cmax, CFW, h2);
  // conv2 attention
  a2_kernel<<<1250, 256, 0, stream>>>(h2, atts2, attd2, as2, ad2);
  softmax2_kernel<<<1250, 256, 0, stream>>>(as2, ad2, rp, csr, p2, sw2, iv2);
  agg2_kernel<<<10000, 256, 0, stream>>>(h2, p2, sw2, iv2, rp, csr, b2, out);
}